// Round 5
// baseline (14626.460 us; speedup 1.0000x reference)
//
#include <hip/hip_runtime.h>
#include <hip/hip_fp16.h>

#define BB 128
#define II 64
#define SS 2048
#define HH 128
#define GG 512   // 4*H
#define OO 64

typedef _Float16 f16x2 __attribute__((ext_vector_type(2)));
union F4H { float4 f4; f16x2 h[4]; };

__device__ __forceinline__ f16x2 pack2(float a, float b) {
    f16x2 r; r.x = (_Float16)a; r.y = (_Float16)b; return r;
}

__device__ __forceinline__ float dot2(f16x2 w, f16x2 v, float c) {
#if __has_builtin(__builtin_amdgcn_fdot2)
    return __builtin_amdgcn_fdot2(w, v, c, false);
#else
    return fmaf((float)w.x, (float)v.x, fmaf((float)w.y, (float)v.y, c));
#endif
}

__device__ __forceinline__ float tanh_f(float v) {
    float a = fabsf(v);
    float e = __expf(-2.0f * a);
    float r = (1.0f - e) * __builtin_amdgcn_rcpf(1.0f + e);
    return v < 0.0f ? -r : r;
}

// quad broadcast: every lane gets lane (quad_base + C)'s value. Pure-VALU DPP.
template<int C>
__device__ __forceinline__ float qb(float v) {
    return __int_as_float(__builtin_amdgcn_mov_dpp(
        __float_as_int(v), 0x55 * C, 0xF, 0xF, true));
}
// DPP row rotate-LEFT by N within each 16-lane row: lane i <- lane (i+N)&15.
// (row_ror:N gives lane i <- lane (i-N)&15 — that direction broke R2.)
template<int N>
__device__ __forceinline__ float rolN(float v) {
    return __int_as_float(__builtin_amdgcn_mov_dpp(
        __float_as_int(v), 0x120 + (16 - N), 0xF, 0xF, true));
}

// LDS-only barrier: avoids __syncthreads()'s vmcnt(0) drain of in-flight
// global loads/stores. LDS ordering (hb/xib/hib/xt) is all we need.
__device__ __forceinline__ void barrier_lds() {
    asm volatile("s_waitcnt lgkmcnt(0)\n\ts_barrier" ::: "memory");
}

// One block per batch element, 512 threads.
// Quad-gate layout: thread j owns gate column (j&3)*128 + (j>>2); gate
// combination and state update are DPP quad-broadcasts (no LDS/barrier).
// 2 raw (lgkm-only) barriers per step. x staged in 16-step LDS tiles.
// R5: Wx_out lives in registers (no wxf LDS reads — the only per-lane LDS
// reads left); projection hoisted to a separate kernel (PROJ_IN=false):
// scan stores h fp16 to workspace, post-GEMM produces out. R4's tile-burst
// reverted (LDS-neutral + scheduling pathology, 2x regression).
template<bool PROJ_IN>
__global__ void __launch_bounds__(512)
__attribute__((amdgpu_waves_per_eu(2)))
nlstm_scan(
    const float* __restrict__ x,
    const float* __restrict__ Wx_out, const float* __restrict__ Wh_out,
    const float* __restrict__ b_out,
    const float* __restrict__ Wx_in, const float* __restrict__ Wh_in,
    const float* __restrict__ b_in,
    const float* __restrict__ W_lin, const float* __restrict__ b_lin,
    float* __restrict__ out, f16x2* __restrict__ hws)
{
    const int b = blockIdx.x;
    const int j = threadIdx.x;
    const int u = j >> 2;          // hidden unit
    const int g = j & 3;           // gate: 0=i 1=f 2=o 3=g
    const int jcol = g * HH + u;   // column of the 512-wide gate matrices

    // x tile: 16 timesteps, row = timestep, entry m = (x[2m][t],x[2m+1][t]).
    __shared__ __align__(16) f16x2 xt[2][16][36];      // 4.5 KB
    __shared__ __align__(16) f16x2 hb[HH / 2];         // h fp16
    __shared__ __align__(16) f16x2 xib[HH / 2];        // x_in fp16
    __shared__ __align__(16) f16x2 hib[HH / 2];        // h_in fp16

    // ---- register/AGPR-resident fp16 weights (column jcol): 224 regs ----
    f16x2 wxo[II / 2];   // Wx_out col jcol (R5: was LDS)
    f16x2 who[HH / 2];   // Wh_out col jcol
    f16x2 wxi[HH / 2];   // Wx_in  col jcol
    f16x2 whi[HH / 2];   // Wh_in  col jcol
#pragma unroll
    for (int m = 0; m < II / 2; ++m)
        wxo[m] = pack2(Wx_out[(2 * m) * GG + jcol], Wx_out[(2 * m + 1) * GG + jcol]);
#pragma unroll
    for (int m = 0; m < HH / 2; ++m)
        who[m] = pack2(Wh_out[(2 * m) * GG + jcol], Wh_out[(2 * m + 1) * GG + jcol]);
#pragma unroll
    for (int m = 0; m < HH / 2; ++m)
        wxi[m] = pack2(Wx_in[(2 * m) * GG + jcol], Wx_in[(2 * m + 1) * GG + jcol]);
#pragma unroll
    for (int m = 0; m < HH / 2; ++m)
        whi[m] = pack2(Wh_in[(2 * m) * GG + jcol], Wh_in[(2 * m + 1) * GG + jcol]);

    const float bo  = b_out[jcol];
    const float bi2 = b_in[jcol];

    // in-scan projection state (fallback mode only)
    const int   pn = j >> 3;
    const int   ps = j & 7;
    float bl = 0.f;
    F4H wl[2];
    if constexpr (PROJ_IN) {
        bl = b_lin[pn];
#pragma unroll
        for (int q = 0; q < 2; ++q) {
            const int c = 2 * ps + q;
#pragma unroll
            for (int r = 0; r < 4; ++r)
                wl[q].h[r] = pack2(W_lin[pn * HH + 8 * c + 2 * r],
                                   W_lin[pn * HH + 8 * c + 2 * r + 1]);
        }
    }

    const float* xrow = x + (size_t)b * II * SS;   // x[b,i,t] = xrow[i*SS + t]
    float* orow = out + (size_t)b * SS * OO;
    f16x2* hrow = hws + (size_t)b * SS * (HH / 2);

    // x tile slot for this thread: entry xm of timestep-row xtl
    const int xm  = j >> 4;    // 0..31
    const int xtl = j & 15;    // 0..15
    const float* xg0 = xrow + (size_t)(2 * xm) * SS + xtl;
    const float* xg1 = xrow + (size_t)(2 * xm + 1) * SS + xtl;

    // tile 0 -> buffer 0
    xt[0][xtl][xm] = pack2(xg0[0], xg1[0]);
    if (j < HH / 2) hb[j] = pack2(0.f, 0.f);
    __syncthreads();   // startup: full sync ok

    float c_reg = 0.f, cn_reg = 0.f;   // quad-replicated cell states (fp32)

    const float4* hb4 = (const float4*)hb;
    const float4* xi4 = (const float4*)xib;
    const float4* hi4 = (const float4*)hib;
    const bool isT = (g == 3);

    float pr0 = 0.f, pr1 = 0.f;        // x-tile prefetch registers

#pragma unroll 1
    for (int t = 0; t < SS; ++t) {
        const int stl = t & 15;        // step's row in the tile
        const int tb  = (t >> 4) & 1;  // current tile buffer

        // ---- prefetch next 16-step x tile (uniform branch, 1/16 steps) ----
        if (stl == 0) {
            const int Tn = (t + 16 < SS) ? t + 16 : t;  // clamp: dead reload
            pr0 = xg0[Tn];
            pr1 = xg1[Tn];
        }

        // ---- outer gates: xt@wxo (regs) + h@who (regs), 4-way ILP ----
        const float4* xc4 = (const float4*)&xt[tb][stl][0];
        float a0 = bo, a1 = 0.f, a2 = 0.f, a3 = 0.f;
#pragma unroll
        for (int c = 0; c < 8; ++c) {
            F4H xu; xu.f4 = xc4[c];
            a0 = dot2(wxo[4 * c + 0], xu.h[0], a0);
            a1 = dot2(wxo[4 * c + 1], xu.h[1], a1);
            a2 = dot2(wxo[4 * c + 2], xu.h[2], a2);
            a3 = dot2(wxo[4 * c + 3], xu.h[3], a3);
        }
#pragma unroll
        for (int c = 0; c < 16; ++c) {
            F4H hu; hu.f4 = hb4[c];
            a0 = dot2(who[4 * c + 0], hu.h[0], a0);
            a1 = dot2(who[4 * c + 1], hu.h[1], a1);
            a2 = dot2(who[4 * c + 2], hu.h[2], a2);
            a3 = dot2(who[4 * c + 3], hu.h[3], a3);
        }
        float acc = (a0 + a1) + (a2 + a3);

        // unified activation: g<3 sigmoid, g==3 tanh = 2*sigm(2x)-1
        float ap = isT ? 2.f * acc : acc;
        float s  = __builtin_amdgcn_rcpf(1.f + __expf(-ap));
        float av = isT ? fmaf(2.f, s, -1.f) : s;

        // gate combination inside the quad (no LDS, no barrier)
        float vi = qb<0>(av), vf = qb<1>(av), vo = qb<2>(av), vg = qb<3>(av);
        float x_in    = vi * vg;        // i * g
        float h_in    = vf * c_reg;     // f * c
        float o_outer = vo;             // kept for h_new

        // ---- in-scan projection of h_{t-1} (fallback mode only) ----
        if constexpr (PROJ_IN) {
            float p0 = 0.f, p1 = 0.f;
            F4H hu0; hu0.f4 = hb4[2 * ps];
            F4H hu1; hu1.f4 = hb4[2 * ps + 1];
            p0 = dot2(wl[0].h[0], hu0.h[0], p0);
            p1 = dot2(wl[0].h[1], hu0.h[1], p1);
            p0 = dot2(wl[0].h[2], hu0.h[2], p0);
            p1 = dot2(wl[0].h[3], hu0.h[3], p1);
            p0 = dot2(wl[1].h[0], hu1.h[0], p0);
            p1 = dot2(wl[1].h[1], hu1.h[1], p1);
            p0 = dot2(wl[1].h[2], hu1.h[2], p0);
            p1 = dot2(wl[1].h[3], hu1.h[3], p1);
            float p = p0 + p1;
            p += rolN<4>(p);   // lane i += lane i+4 (ps==0 stays in-group)
            p += rolN<2>(p);
            p += rolN<1>(p);
            if (ps == 0 && t > 0) orow[(size_t)(t - 1) * OO + pn] = p + bl;
        }

        // write x_in/h_in pairs (lane j=8k packs units 2k,2k+1 via DPP rol4)
        float xin_n = rolN<4>(x_in);
        float hin_n = rolN<4>(h_in);
        if ((j & 7) == 0) {
            xib[u >> 1] = pack2(x_in, xin_n);
            hib[u >> 1] = pack2(h_in, hin_n);
        }
        barrier_lds();   // B_a: xib/hib visible; hb readers done before write

        // ---- inner gates: 8 accumulators (chain depth 16) ----
        float c0 = bi2, c1 = 0.f, c2 = 0.f, c3 = 0.f;
        float d0 = 0.f, d1 = 0.f, d2 = 0.f, d3 = 0.f;
#pragma unroll
        for (int c = 0; c < 16; ++c) {
            F4H xu; xu.f4 = xi4[c];
            c0 = dot2(wxi[4 * c + 0], xu.h[0], c0);
            c1 = dot2(wxi[4 * c + 1], xu.h[1], c1);
            c2 = dot2(wxi[4 * c + 2], xu.h[2], c2);
            c3 = dot2(wxi[4 * c + 3], xu.h[3], c3);
        }
#pragma unroll
        for (int c = 0; c < 16; ++c) {
            F4H hu; hu.f4 = hi4[c];
            d0 = dot2(whi[4 * c + 0], hu.h[0], d0);
            d1 = dot2(whi[4 * c + 1], hu.h[1], d1);
            d2 = dot2(whi[4 * c + 2], hu.h[2], d2);
            d3 = dot2(whi[4 * c + 3], hu.h[3], d3);
        }
        float acc2 = ((c0 + c1) + (c2 + c3)) + ((d0 + d1) + (d2 + d3));

        float ap2 = isT ? 2.f * acc2 : acc2;
        float s2  = __builtin_amdgcn_rcpf(1.f + __expf(-ap2));
        float av2 = isT ? fmaf(2.f, s2, -1.f) : s2;

        // state update inside the quad (no LDS, no barrier)
        float ii = qb<0>(av2), fi = qb<1>(av2), oi = qb<2>(av2), gg = qb<3>(av2);
        float cn_new = fmaf(fi, cn_reg, ii * gg);
        cn_reg = cn_new;
        float c_new = oi * tanh_f(cn_new);
        c_reg = c_new;
        float h_new = o_outer * tanh_f(c_new);

        float hn_n = rolN<4>(h_new);
        if ((j & 7) == 0) {
            f16x2 hp = pack2(h_new, hn_n);
            hb[u >> 1] = hp;
            if constexpr (!PROJ_IN)
                hrow[(size_t)t * (HH / 2) + (j >> 3)] = hp;  // h_t -> ws
        }
        // stash prefetched tile into the other buffer (last read pre-B_a)
        if (stl == 0) xt[tb ^ 1][xtl][xm] = pack2(pr0, pr1);
        barrier_lds();   // B_b: h_t (+ new tile) visible
    }

    // ---- final projection: out[S-1] from h_{S-1} (fallback mode only) ----
    if constexpr (PROJ_IN) {
        float p0 = 0.f, p1 = 0.f;
        F4H hu0; hu0.f4 = hb4[2 * ps];
        F4H hu1; hu1.f4 = hb4[2 * ps + 1];
        p0 = dot2(wl[0].h[0], hu0.h[0], p0);
        p1 = dot2(wl[0].h[1], hu0.h[1], p1);
        p0 = dot2(wl[0].h[2], hu0.h[2], p0);
        p1 = dot2(wl[0].h[3], hu0.h[3], p1);
        p0 = dot2(wl[1].h[0], hu1.h[0], p0);
        p1 = dot2(wl[1].h[1], hu1.h[1], p1);
        p0 = dot2(wl[1].h[2], hu1.h[2], p0);
        p1 = dot2(wl[1].h[3], hu1.h[3], p1);
        float p = p0 + p1;
        p += rolN<4>(p);
        p += rolN<2>(p);
        p += rolN<1>(p);
        if (ps == 0) orow[(size_t)(SS - 1) * OO + pn] = p + bl;
    }
}

// Post-scan projection: out[r, n] = h[r,:] @ W_lin[n,:] + b_lin[n].
// 512 blocks x 256 threads; wave = 64 lanes = all 64 output cols of one row
// (h row reads are wave-uniform global loads -> single transaction).
// W_lin row n in registers; no LDS at all. 128 rows per wave.
__global__ void __launch_bounds__(256)
nlstm_proj(const f16x2* __restrict__ hws, const float* __restrict__ W_lin,
           const float* __restrict__ b_lin, float* __restrict__ out)
{
    const int n  = threadIdx.x & 63;   // output column
    const int rg = threadIdx.x >> 6;   // wave = row subgroup

    f16x2 wn[HH / 2];                  // W_lin row n, fp16 pairs (64 regs)
#pragma unroll
    for (int k = 0; k < HH / 2; ++k)
        wn[k] = pack2(W_lin[n * HH + 2 * k], W_lin[n * HH + 2 * k + 1]);
    const float bl = b_lin[n];

    const size_t r0 = (size_t)blockIdx.x * 512 + (size_t)rg * 128;
#pragma unroll 1
    for (int rr = 0; rr < 128; ++rr) {
        const size_t r = r0 + rr;
        const float4* hr = (const float4*)(hws + r * (HH / 2));
        float p0 = 0.f, p1 = 0.f, p2 = 0.f, p3 = 0.f;
#pragma unroll
        for (int c = 0; c < 16; ++c) {
            F4H hu; hu.f4 = hr[c];     // uniform across the wave
            p0 = dot2(wn[4 * c + 0], hu.h[0], p0);
            p1 = dot2(wn[4 * c + 1], hu.h[1], p1);
            p2 = dot2(wn[4 * c + 2], hu.h[2], p2);
            p3 = dot2(wn[4 * c + 3], hu.h[3], p3);
        }
        out[r * OO + n] = ((p0 + p1) + (p2 + p3)) + bl;
    }
}

extern "C" void kernel_launch(void* const* d_in, const int* in_sizes, int n_in,
                              void* d_out, int out_size, void* d_ws, size_t ws_size,
                              hipStream_t stream) {
    (void)in_sizes; (void)n_in; (void)out_size;
    const float* x      = (const float*)d_in[0];
    const float* Wx_out = (const float*)d_in[1];
    const float* Wh_out = (const float*)d_in[2];
    const float* b_out  = (const float*)d_in[3];
    const float* Wx_in  = (const float*)d_in[4];
    const float* Wh_in  = (const float*)d_in[5];
    const float* b_in   = (const float*)d_in[6];
    const float* W_lin  = (const float*)d_in[7];
    const float* b_lin  = (const float*)d_in[8];
    float* out = (float*)d_out;

    const size_t h_bytes = (size_t)BB * SS * (HH / 2) * sizeof(f16x2); // 64 MB
    if (d_ws != nullptr && ws_size >= h_bytes) {
        f16x2* hws = (f16x2*)d_ws;
        nlstm_scan<false><<<dim3(BB), dim3(512), 0, stream>>>(
            x, Wx_out, Wh_out, b_out, Wx_in, Wh_in, b_in, W_lin, b_lin,
            out, hws);
        nlstm_proj<<<dim3(512), dim3(256), 0, stream>>>(hws, W_lin, b_lin, out);
    } else {
        nlstm_scan<true><<<dim3(BB), dim3(512), 0, stream>>>(
            x, Wx_out, Wh_out, b_out, Wx_in, Wh_in, b_in, W_lin, b_lin,
            out, (f16x2*)nullptr);
    }
}

// Round 6
// 7516.264 us; speedup vs baseline: 1.9460x; 1.9460x over previous
//
#include <hip/hip_runtime.h>
#include <hip/hip_fp16.h>

#define BB 128
#define II 64
#define SS 2048
#define HH 128
#define GG 512   // 4*H
#define OO 64

typedef _Float16 f16x2 __attribute__((ext_vector_type(2)));
union F4H { float4 f4; f16x2 h[4]; };

__device__ __forceinline__ f16x2 pack2(float a, float b) {
    f16x2 r; r.x = (_Float16)a; r.y = (_Float16)b; return r;
}

__device__ __forceinline__ float dot2(f16x2 w, f16x2 v, float c) {
#if __has_builtin(__builtin_amdgcn_fdot2)
    return __builtin_amdgcn_fdot2(w, v, c, false);
#else
    return fmaf((float)w.x, (float)v.x, fmaf((float)w.y, (float)v.y, c));
#endif
}

__device__ __forceinline__ float tanh_f(float v) {
    float a = fabsf(v);
    float e = __expf(-2.0f * a);
    float r = (1.0f - e) * __builtin_amdgcn_rcpf(1.0f + e);
    return v < 0.0f ? -r : r;
}

// quad broadcast: every lane gets lane (quad_base + C)'s value. Pure-VALU DPP.
template<int C>
__device__ __forceinline__ float qb(float v) {
    return __int_as_float(__builtin_amdgcn_mov_dpp(
        __float_as_int(v), 0x55 * C, 0xF, 0xF, true));
}
// DPP row rotate-LEFT by N within each 16-lane row: lane i <- lane (i+N)&15.
// (row_ror:N gives lane i <- lane (i-N)&15 — that direction broke R2.)
template<int N>
__device__ __forceinline__ float rolN(float v) {
    return __int_as_float(__builtin_amdgcn_mov_dpp(
        __float_as_int(v), 0x120 + (16 - N), 0xF, 0xF, true));
}

// LDS-only barrier: avoids __syncthreads()'s vmcnt(0) drain of in-flight
// global loads/stores. LDS ordering (hb/xib/hib/xt) is all we need.
__device__ __forceinline__ void barrier_lds() {
    asm volatile("s_waitcnt lgkmcnt(0)\n\ts_barrier" ::: "memory");
}

// One block per batch element, 512 threads.
// Quad-gate layout: thread j owns gate column (j&3)*128 + (j>>2); gate
// combination and state update are DPP quad-broadcasts (no LDS/barrier).
// 2 raw (lgkm-only) barriers per step. x staged in 16-step LDS tiles.
// R6: EXACT R3 register/LDS layout (Wx_out in LDS wxf — R5's +32 regs blew
// the waves_per_eu(2) unified-file cap -> scratch spill on the critical
// path, 3.6x regression) + R5's projection hoist (PROJ_IN=false: scan
// stores h fp16 to ws, post-GEMM kernel produces out; frees 16 regs and
// 13 ops/step).
template<bool PROJ_IN>
__global__ void __launch_bounds__(512)
__attribute__((amdgpu_waves_per_eu(2)))
nlstm_scan(
    const float* __restrict__ x,
    const float* __restrict__ Wx_out, const float* __restrict__ Wh_out,
    const float* __restrict__ b_out,
    const float* __restrict__ Wx_in, const float* __restrict__ Wh_in,
    const float* __restrict__ b_in,
    const float* __restrict__ W_lin, const float* __restrict__ b_lin,
    float* __restrict__ out, f16x2* __restrict__ hws)
{
    const int b = blockIdx.x;
    const int j = threadIdx.x;
    const int u = j >> 2;          // hidden unit
    const int g = j & 3;           // gate: 0=i 1=f 2=o 3=g
    const int jcol = g * HH + u;   // column of the 512-wide gate matrices

    __shared__ __align__(16) float4 wxf[8 * 512];      // Wx_out fp16, 64 KB
    // x tile: 16 timesteps, row = timestep, entry m = (x[2m][t],x[2m+1][t]).
    __shared__ __align__(16) f16x2 xt[2][16][36];      // 4.5 KB
    __shared__ __align__(16) f16x2 hb[HH / 2];         // h fp16
    __shared__ __align__(16) f16x2 xib[HH / 2];        // x_in fp16
    __shared__ __align__(16) f16x2 hib[HH / 2];        // h_in fp16

    // ---- register/AGPR-resident fp16 weights (column jcol): 192 regs ----
    f16x2 who[HH / 2];   // Wh_out col jcol
    f16x2 wxi[HH / 2];   // Wx_in  col jcol
    f16x2 whi[HH / 2];   // Wh_in  col jcol
#pragma unroll
    for (int m = 0; m < HH / 2; ++m)
        who[m] = pack2(Wh_out[(2 * m) * GG + jcol], Wh_out[(2 * m + 1) * GG + jcol]);
#pragma unroll
    for (int m = 0; m < HH / 2; ++m)
        wxi[m] = pack2(Wx_in[(2 * m) * GG + jcol], Wx_in[(2 * m + 1) * GG + jcol]);
#pragma unroll
    for (int m = 0; m < HH / 2; ++m)
        whi[m] = pack2(Wh_in[(2 * m) * GG + jcol], Wh_in[(2 * m + 1) * GG + jcol]);

    const float bo  = b_out[jcol];
    const float bi2 = b_in[jcol];

    // in-scan projection state (fallback mode only)
    const int   pn = j >> 3;
    const int   ps = j & 7;
    float bl = 0.f;
    F4H wl[2];
    if constexpr (PROJ_IN) {
        bl = b_lin[pn];
#pragma unroll
        for (int q = 0; q < 2; ++q) {
            const int c = 2 * ps + q;
#pragma unroll
            for (int r = 0; r < 4; ++r)
                wl[q].h[r] = pack2(W_lin[pn * HH + 8 * c + 2 * r],
                                   W_lin[pn * HH + 8 * c + 2 * r + 1]);
        }
    }

    // Wx_out column jcol -> LDS slot j, fp16 (lane-consecutive b128 reads,
    // measured 0 conflicts)
#pragma unroll
    for (int c = 0; c < 8; ++c) {
        F4H w4;
#pragma unroll
        for (int q = 0; q < 4; ++q)
            w4.h[q] = pack2(Wx_out[(8 * c + 2 * q) * GG + jcol],
                            Wx_out[(8 * c + 2 * q + 1) * GG + jcol]);
        wxf[c * 512 + j] = w4.f4;
    }

    const float* xrow = x + (size_t)b * II * SS;   // x[b,i,t] = xrow[i*SS + t]
    float* orow = out + (size_t)b * SS * OO;
    f16x2* hrow = hws + (size_t)b * SS * (HH / 2);

    // x tile slot for this thread: entry xm of timestep-row xtl
    const int xm  = j >> 4;    // 0..31
    const int xtl = j & 15;    // 0..15
    const float* xg0 = xrow + (size_t)(2 * xm) * SS + xtl;
    const float* xg1 = xrow + (size_t)(2 * xm + 1) * SS + xtl;

    // tile 0 -> buffer 0
    xt[0][xtl][xm] = pack2(xg0[0], xg1[0]);
    if (j < HH / 2) hb[j] = pack2(0.f, 0.f);
    __syncthreads();   // startup: full sync ok

    float c_reg = 0.f, cn_reg = 0.f;   // quad-replicated cell states (fp32)

    const float4* hb4 = (const float4*)hb;
    const float4* xi4 = (const float4*)xib;
    const float4* hi4 = (const float4*)hib;
    const bool isT = (g == 3);

    float pr0 = 0.f, pr1 = 0.f;        // x-tile prefetch registers

#pragma unroll 1
    for (int t = 0; t < SS; ++t) {
        const int stl = t & 15;        // step's row in the tile
        const int tb  = (t >> 4) & 1;  // current tile buffer

        // ---- prefetch next 16-step x tile (uniform branch, 1/16 steps) ----
        if (stl == 0) {
            const int Tn = (t + 16 < SS) ? t + 16 : t;  // clamp: dead reload
            pr0 = xg0[Tn];
            pr1 = xg1[Tn];
        }

        // ---- outer gates: col jcol of xt@Wx_out + h@Wh_out + b, 4-way ILP ----
        const float4* xc4 = (const float4*)&xt[tb][stl][0];
        float a0 = bo, a1 = 0.f, a2 = 0.f, a3 = 0.f;
#pragma unroll
        for (int c = 0; c < 8; ++c) {
            F4H xu; xu.f4 = xc4[c];
            F4H wu; wu.f4 = wxf[c * 512 + j];
            a0 = dot2(wu.h[0], xu.h[0], a0);
            a1 = dot2(wu.h[1], xu.h[1], a1);
            a2 = dot2(wu.h[2], xu.h[2], a2);
            a3 = dot2(wu.h[3], xu.h[3], a3);
        }
#pragma unroll
        for (int c = 0; c < 16; ++c) {
            F4H hu; hu.f4 = hb4[c];
            a0 = dot2(who[4 * c + 0], hu.h[0], a0);
            a1 = dot2(who[4 * c + 1], hu.h[1], a1);
            a2 = dot2(who[4 * c + 2], hu.h[2], a2);
            a3 = dot2(who[4 * c + 3], hu.h[3], a3);
        }
        float acc = (a0 + a1) + (a2 + a3);

        // unified activation: g<3 sigmoid, g==3 tanh = 2*sigm(2x)-1
        float ap = isT ? 2.f * acc : acc;
        float s  = __builtin_amdgcn_rcpf(1.f + __expf(-ap));
        float av = isT ? fmaf(2.f, s, -1.f) : s;

        // gate combination inside the quad (no LDS, no barrier)
        float vi = qb<0>(av), vf = qb<1>(av), vo = qb<2>(av), vg = qb<3>(av);
        float x_in    = vi * vg;        // i * g
        float h_in    = vf * c_reg;     // f * c
        float o_outer = vo;             // kept for h_new

        // ---- in-scan projection of h_{t-1} (fallback mode only) ----
        if constexpr (PROJ_IN) {
            float p0 = 0.f, p1 = 0.f;
            F4H hu0; hu0.f4 = hb4[2 * ps];
            F4H hu1; hu1.f4 = hb4[2 * ps + 1];
            p0 = dot2(wl[0].h[0], hu0.h[0], p0);
            p1 = dot2(wl[0].h[1], hu0.h[1], p1);
            p0 = dot2(wl[0].h[2], hu0.h[2], p0);
            p1 = dot2(wl[0].h[3], hu0.h[3], p1);
            p0 = dot2(wl[1].h[0], hu1.h[0], p0);
            p1 = dot2(wl[1].h[1], hu1.h[1], p1);
            p0 = dot2(wl[1].h[2], hu1.h[2], p0);
            p1 = dot2(wl[1].h[3], hu1.h[3], p1);
            float p = p0 + p1;
            p += rolN<4>(p);   // lane i += lane i+4 (ps==0 stays in-group)
            p += rolN<2>(p);
            p += rolN<1>(p);
            if (ps == 0 && t > 0) orow[(size_t)(t - 1) * OO + pn] = p + bl;
        }

        // write x_in/h_in pairs (lane j=8k packs units 2k,2k+1 via DPP rol4)
        float xin_n = rolN<4>(x_in);
        float hin_n = rolN<4>(h_in);
        if ((j & 7) == 0) {
            xib[u >> 1] = pack2(x_in, xin_n);
            hib[u >> 1] = pack2(h_in, hin_n);
        }
        barrier_lds();   // B_a: xib/hib visible; hb readers done before write

        // ---- inner gates: 8 accumulators (chain depth 16) ----
        float c0 = bi2, c1 = 0.f, c2 = 0.f, c3 = 0.f;
        float d0 = 0.f, d1 = 0.f, d2 = 0.f, d3 = 0.f;
#pragma unroll
        for (int c = 0; c < 16; ++c) {
            F4H xu; xu.f4 = xi4[c];
            c0 = dot2(wxi[4 * c + 0], xu.h[0], c0);
            c1 = dot2(wxi[4 * c + 1], xu.h[1], c1);
            c2 = dot2(wxi[4 * c + 2], xu.h[2], c2);
            c3 = dot2(wxi[4 * c + 3], xu.h[3], c3);
        }
#pragma unroll
        for (int c = 0; c < 16; ++c) {
            F4H hu; hu.f4 = hi4[c];
            d0 = dot2(whi[4 * c + 0], hu.h[0], d0);
            d1 = dot2(whi[4 * c + 1], hu.h[1], d1);
            d2 = dot2(whi[4 * c + 2], hu.h[2], d2);
            d3 = dot2(whi[4 * c + 3], hu.h[3], d3);
        }
        float acc2 = ((c0 + c1) + (c2 + c3)) + ((d0 + d1) + (d2 + d3));

        float ap2 = isT ? 2.f * acc2 : acc2;
        float s2  = __builtin_amdgcn_rcpf(1.f + __expf(-ap2));
        float av2 = isT ? fmaf(2.f, s2, -1.f) : s2;

        // state update inside the quad (no LDS, no barrier)
        float ii = qb<0>(av2), fi = qb<1>(av2), oi = qb<2>(av2), gg = qb<3>(av2);
        float cn_new = fmaf(fi, cn_reg, ii * gg);
        cn_reg = cn_new;
        float c_new = oi * tanh_f(cn_new);
        c_reg = c_new;
        float h_new = o_outer * tanh_f(c_new);

        float hn_n = rolN<4>(h_new);
        if ((j & 7) == 0) {
            f16x2 hp = pack2(h_new, hn_n);
            hb[u >> 1] = hp;
            if constexpr (!PROJ_IN)
                hrow[(size_t)t * (HH / 2) + (j >> 3)] = hp;  // h_t -> ws
        }
        // stash prefetched tile into the other buffer (last read pre-B_a)
        if (stl == 0) xt[tb ^ 1][xtl][xm] = pack2(pr0, pr1);
        barrier_lds();   // B_b: h_t (+ new tile) visible
    }

    // ---- final projection: out[S-1] from h_{S-1} (fallback mode only) ----
    if constexpr (PROJ_IN) {
        float p0 = 0.f, p1 = 0.f;
        F4H hu0; hu0.f4 = hb4[2 * ps];
        F4H hu1; hu1.f4 = hb4[2 * ps + 1];
        p0 = dot2(wl[0].h[0], hu0.h[0], p0);
        p1 = dot2(wl[0].h[1], hu0.h[1], p1);
        p0 = dot2(wl[0].h[2], hu0.h[2], p0);
        p1 = dot2(wl[0].h[3], hu0.h[3], p1);
        p0 = dot2(wl[1].h[0], hu1.h[0], p0);
        p1 = dot2(wl[1].h[1], hu1.h[1], p1);
        p0 = dot2(wl[1].h[2], hu1.h[2], p0);
        p1 = dot2(wl[1].h[3], hu1.h[3], p1);
        float p = p0 + p1;
        p += rolN<4>(p);
        p += rolN<2>(p);
        p += rolN<1>(p);
        if (ps == 0) orow[(size_t)(SS - 1) * OO + pn] = p + bl;
    }
}

// Post-scan projection: out[r, n] = h[r,:] @ W_lin[n,:] + b_lin[n].
// 512 blocks x 256 threads; wave = 64 lanes = all 64 output cols of one row
// (h row reads are wave-uniform global loads, served by L3 since hws was
// just written). W_lin row n in registers; no LDS. 128 rows per wave.
__global__ void __launch_bounds__(256)
nlstm_proj(const f16x2* __restrict__ hws, const float* __restrict__ W_lin,
           const float* __restrict__ b_lin, float* __restrict__ out)
{
    const int n  = threadIdx.x & 63;   // output column
    const int rg = threadIdx.x >> 6;   // wave = row subgroup

    f16x2 wn[HH / 2];                  // W_lin row n, fp16 pairs (64 regs)
#pragma unroll
    for (int k = 0; k < HH / 2; ++k)
        wn[k] = pack2(W_lin[n * HH + 2 * k], W_lin[n * HH + 2 * k + 1]);
    const float bl = b_lin[n];

    const size_t r0 = (size_t)blockIdx.x * 512 + (size_t)rg * 128;
#pragma unroll 1
    for (int rr = 0; rr < 128; ++rr) {
        const size_t r = r0 + rr;
        const float4* hr = (const float4*)(hws + r * (HH / 2));
        float p0 = 0.f, p1 = 0.f, p2 = 0.f, p3 = 0.f;
#pragma unroll
        for (int c = 0; c < 16; ++c) {
            F4H hu; hu.f4 = hr[c];     // uniform across the wave
            p0 = dot2(wn[4 * c + 0], hu.h[0], p0);
            p1 = dot2(wn[4 * c + 1], hu.h[1], p1);
            p2 = dot2(wn[4 * c + 2], hu.h[2], p2);
            p3 = dot2(wn[4 * c + 3], hu.h[3], p3);
        }
        out[r * OO + n] = ((p0 + p1) + (p2 + p3)) + bl;
    }
}

extern "C" void kernel_launch(void* const* d_in, const int* in_sizes, int n_in,
                              void* d_out, int out_size, void* d_ws, size_t ws_size,
                              hipStream_t stream) {
    (void)in_sizes; (void)n_in; (void)out_size;
    const float* x      = (const float*)d_in[0];
    const float* Wx_out = (const float*)d_in[1];
    const float* Wh_out = (const float*)d_in[2];
    const float* b_out  = (const float*)d_in[3];
    const float* Wx_in  = (const float*)d_in[4];
    const float* Wh_in  = (const float*)d_in[5];
    const float* b_in   = (const float*)d_in[6];
    const float* W_lin  = (const float*)d_in[7];
    const float* b_lin  = (const float*)d_in[8];
    float* out = (float*)d_out;

    const size_t h_bytes = (size_t)BB * SS * (HH / 2) * sizeof(f16x2); // 64 MB
    if (d_ws != nullptr && ws_size >= h_bytes) {
        f16x2* hws = (f16x2*)d_ws;
        nlstm_scan<false><<<dim3(BB), dim3(512), 0, stream>>>(
            x, Wx_out, Wh_out, b_out, Wx_in, Wh_in, b_in, W_lin, b_lin,
            out, hws);
        nlstm_proj<<<dim3(512), dim3(256), 0, stream>>>(hws, W_lin, b_lin, out);
    } else {
        nlstm_scan<true><<<dim3(BB), dim3(512), 0, stream>>>(
            x, Wx_out, Wh_out, b_out, Wx_in, Wh_in, b_in, W_lin, b_lin,
            out, (f16x2*)nullptr);
    }
}

// Round 7
// 4102.893 us; speedup vs baseline: 3.5649x; 1.8319x over previous
//
#include <hip/hip_runtime.h>
#include <hip/hip_fp16.h>

#define BB 128
#define II 64
#define SS 2048
#define HH 128
#define GG 512   // 4*H
#define OO 64

typedef _Float16 f16x2 __attribute__((ext_vector_type(2)));
union F4H { float4 f4; f16x2 h[4]; };

__device__ __forceinline__ f16x2 pack2(float a, float b) {
    f16x2 r; r.x = (_Float16)a; r.y = (_Float16)b; return r;
}

__device__ __forceinline__ float dot2(f16x2 w, f16x2 v, float c) {
#if __has_builtin(__builtin_amdgcn_fdot2)
    return __builtin_amdgcn_fdot2(w, v, c, false);
#else
    return fmaf((float)w.x, (float)v.x, fmaf((float)w.y, (float)v.y, c));
#endif
}

__device__ __forceinline__ float tanh_f(float v) {
    float a = fabsf(v);
    float e = __expf(-2.0f * a);
    float r = (1.0f - e) * __builtin_amdgcn_rcpf(1.0f + e);
    return v < 0.0f ? -r : r;
}

// quad broadcast: every lane gets lane (quad_base + C)'s value. Pure-VALU DPP.
template<int C>
__device__ __forceinline__ float qb(float v) {
    return __int_as_float(__builtin_amdgcn_mov_dpp(
        __float_as_int(v), 0x55 * C, 0xF, 0xF, true));
}
// DPP row rotate-LEFT by N within each 16-lane row: lane i <- lane (i+N)&15.
// (row_ror:N gives lane i <- lane (i-N)&15 — that direction broke R2.)
template<int N>
__device__ __forceinline__ float rolN(float v) {
    return __int_as_float(__builtin_amdgcn_mov_dpp(
        __float_as_int(v), 0x120 + (16 - N), 0xF, 0xF, true));
}

// LDS-only barrier: avoids __syncthreads()'s vmcnt(0) drain of in-flight
// global loads/stores. LDS ordering (hb/xib/hib/xt) is all we need.
__device__ __forceinline__ void barrier_lds() {
    asm volatile("s_waitcnt lgkmcnt(0)\n\ts_barrier" ::: "memory");
}

// One block per batch element, 512 threads.
// Quad-gate layout: thread j owns gate column (j&3)*128 + (j>>2); gate
// combination and state update are DPP quad-broadcasts (no LDS/barrier).
// 2 raw (lgkm-only) barriers per step. x staged in 16-step LDS tiles.
//
// REGISTER CLIFF (R4/R5/R6 lesson): this kernel sits exactly at the 256-reg
// unified VGPR/AGPR cap. ANY net-positive live-register change (8-way
// accumulator splits, extra weight arrays, burst buffers) spills
// loop-resident values to L2-scratch (invisible in FETCH/WRITE!) and costs
// ~2x. Loop body below is byte-equivalent to R3's proven 4034 us version.
// R7 delta vs R3: projection hoisted out (PROJ_IN=false drops wl[8]+bl =
// register-NEGATIVE; h stored to ws via wave-uniform SGPR base + 2 VALU).
template<bool PROJ_IN>
__global__ void __launch_bounds__(512)
__attribute__((amdgpu_waves_per_eu(2)))
nlstm_scan(
    const float* __restrict__ x,
    const float* __restrict__ Wx_out, const float* __restrict__ Wh_out,
    const float* __restrict__ b_out,
    const float* __restrict__ Wx_in, const float* __restrict__ Wh_in,
    const float* __restrict__ b_in,
    const float* __restrict__ W_lin, const float* __restrict__ b_lin,
    float* __restrict__ out, f16x2* __restrict__ hws)
{
    const int b = blockIdx.x;
    const int j = threadIdx.x;
    const int u = j >> 2;          // hidden unit
    const int g = j & 3;           // gate: 0=i 1=f 2=o 3=g
    const int jcol = g * HH + u;   // column of the 512-wide gate matrices

    __shared__ __align__(16) float4 wxf[8 * 512];      // Wx_out fp16, 64 KB
    // x tile: 16 timesteps, row = timestep, entry m = (x[2m][t],x[2m+1][t]).
    __shared__ __align__(16) f16x2 xt[2][16][36];      // 4.5 KB
    __shared__ __align__(16) f16x2 hb[HH / 2];         // h fp16
    __shared__ __align__(16) f16x2 xib[HH / 2];        // x_in fp16
    __shared__ __align__(16) f16x2 hib[HH / 2];        // h_in fp16

    // ---- register/AGPR-resident fp16 weights (column jcol): 192 regs ----
    f16x2 who[HH / 2];   // Wh_out col jcol
    f16x2 wxi[HH / 2];   // Wx_in  col jcol
    f16x2 whi[HH / 2];   // Wh_in  col jcol
#pragma unroll
    for (int m = 0; m < HH / 2; ++m)
        who[m] = pack2(Wh_out[(2 * m) * GG + jcol], Wh_out[(2 * m + 1) * GG + jcol]);
#pragma unroll
    for (int m = 0; m < HH / 2; ++m)
        wxi[m] = pack2(Wx_in[(2 * m) * GG + jcol], Wx_in[(2 * m + 1) * GG + jcol]);
#pragma unroll
    for (int m = 0; m < HH / 2; ++m)
        whi[m] = pack2(Wh_in[(2 * m) * GG + jcol], Wh_in[(2 * m + 1) * GG + jcol]);

    const float bo  = b_out[jcol];
    const float bi2 = b_in[jcol];

    // in-scan projection state (fallback mode only)
    const int   pn = j >> 3;
    const int   ps = j & 7;
    float bl = 0.f;
    F4H wl[2];
    if constexpr (PROJ_IN) {
        bl = b_lin[pn];
#pragma unroll
        for (int q = 0; q < 2; ++q) {
            const int c = 2 * ps + q;
#pragma unroll
            for (int r = 0; r < 4; ++r)
                wl[q].h[r] = pack2(W_lin[pn * HH + 8 * c + 2 * r],
                                   W_lin[pn * HH + 8 * c + 2 * r + 1]);
        }
    }

    // Wx_out column jcol -> LDS slot j, fp16 (lane-consecutive b128 reads,
    // measured 0 conflicts)
#pragma unroll
    for (int c = 0; c < 8; ++c) {
        F4H w4;
#pragma unroll
        for (int q = 0; q < 4; ++q)
            w4.h[q] = pack2(Wx_out[(8 * c + 2 * q) * GG + jcol],
                            Wx_out[(8 * c + 2 * q + 1) * GG + jcol]);
        wxf[c * 512 + j] = w4.f4;
    }

    const float* xrow = x + (size_t)b * II * SS;   // x[b,i,t] = xrow[i*SS + t]
    float* orow = out + (size_t)b * SS * OO;
    f16x2* hrow = hws + (size_t)b * SS * (HH / 2);  // wave-uniform -> SGPRs

    // x tile slot for this thread: entry xm of timestep-row xtl
    const int xm  = j >> 4;    // 0..31
    const int xtl = j & 15;    // 0..15
    const float* xg0 = xrow + (size_t)(2 * xm) * SS + xtl;
    const float* xg1 = xrow + (size_t)(2 * xm + 1) * SS + xtl;

    // tile 0 -> buffer 0
    xt[0][xtl][xm] = pack2(xg0[0], xg1[0]);
    if (j < HH / 2) hb[j] = pack2(0.f, 0.f);
    __syncthreads();   // startup: full sync ok

    float c_reg = 0.f, cn_reg = 0.f;   // quad-replicated cell states (fp32)

    const float4* hb4 = (const float4*)hb;
    const float4* xi4 = (const float4*)xib;
    const float4* hi4 = (const float4*)hib;
    const bool isT = (g == 3);

    float pr0 = 0.f, pr1 = 0.f;        // x-tile prefetch registers

#pragma unroll 1
    for (int t = 0; t < SS; ++t) {
        const int stl = t & 15;        // step's row in the tile
        const int tb  = (t >> 4) & 1;  // current tile buffer

        // ---- prefetch next 16-step x tile (uniform branch, 1/16 steps) ----
        if (stl == 0) {
            const int Tn = (t + 16 < SS) ? t + 16 : t;  // clamp: dead reload
            pr0 = xg0[Tn];
            pr1 = xg1[Tn];
        }

        // ---- outer gates: col jcol of xt@Wx_out + h@Wh_out + b, 4-way ILP ----
        const float4* xc4 = (const float4*)&xt[tb][stl][0];
        float a0 = 0.f, a1 = 0.f, a2 = 0.f, a3 = 0.f;
#pragma unroll
        for (int c = 0; c < 8; ++c) {
            F4H xu; xu.f4 = xc4[c];
            F4H wu; wu.f4 = wxf[c * 512 + j];
            a0 = dot2(wu.h[0], xu.h[0], a0);
            a1 = dot2(wu.h[1], xu.h[1], a1);
            a2 = dot2(wu.h[2], xu.h[2], a2);
            a3 = dot2(wu.h[3], xu.h[3], a3);
        }
#pragma unroll
        for (int c = 0; c < 16; ++c) {
            F4H hu; hu.f4 = hb4[c];
            a0 = dot2(who[4 * c + 0], hu.h[0], a0);
            a1 = dot2(who[4 * c + 1], hu.h[1], a1);
            a2 = dot2(who[4 * c + 2], hu.h[2], a2);
            a3 = dot2(who[4 * c + 3], hu.h[3], a3);
        }
        float acc = ((a0 + a1) + (a2 + a3)) + bo;

        // unified activation: g<3 sigmoid, g==3 tanh = 2*sigm(2x)-1
        float ap = isT ? 2.f * acc : acc;
        float s  = __builtin_amdgcn_rcpf(1.f + __expf(-ap));
        float av = isT ? fmaf(2.f, s, -1.f) : s;

        // gate combination inside the quad (no LDS, no barrier)
        float vi = qb<0>(av), vf = qb<1>(av), vo = qb<2>(av), vg = qb<3>(av);
        float x_in    = vi * vg;        // i * g
        float h_in    = vf * c_reg;     // f * c
        float o_outer = vo;             // kept for h_new

        // ---- in-scan projection of h_{t-1} (fallback mode only) ----
        if constexpr (PROJ_IN) {
            float p0 = 0.f, p1 = 0.f;
            F4H hu0; hu0.f4 = hb4[2 * ps];
            F4H hu1; hu1.f4 = hb4[2 * ps + 1];
            p0 = dot2(wl[0].h[0], hu0.h[0], p0);
            p1 = dot2(wl[0].h[1], hu0.h[1], p1);
            p0 = dot2(wl[0].h[2], hu0.h[2], p0);
            p1 = dot2(wl[0].h[3], hu0.h[3], p1);
            p0 = dot2(wl[1].h[0], hu1.h[0], p0);
            p1 = dot2(wl[1].h[1], hu1.h[1], p1);
            p0 = dot2(wl[1].h[2], hu1.h[2], p0);
            p1 = dot2(wl[1].h[3], hu1.h[3], p1);
            float p = p0 + p1;
            p += rolN<4>(p);   // lane i += lane i+4 (ps==0 stays in-group)
            p += rolN<2>(p);
            p += rolN<1>(p);
            if (ps == 0 && t > 0) orow[(size_t)(t - 1) * OO + pn] = p + bl;
        }

        // write x_in/h_in pairs (lane j=8k packs units 2k,2k+1 via DPP rol4)
        float xin_n = rolN<4>(x_in);
        float hin_n = rolN<4>(h_in);
        if ((j & 7) == 0) {
            xib[u >> 1] = pack2(x_in, xin_n);
            hib[u >> 1] = pack2(h_in, hin_n);
        }
        barrier_lds();   // B_a: xib/hib visible; hb readers done before write

        // ---- inner gates: R3's exact 4 shared accumulators (reg-minimal) ----
        float b0 = 0.f, b1 = 0.f, b2 = 0.f, b3 = 0.f;
#pragma unroll
        for (int c = 0; c < 16; ++c) {
            F4H xu; xu.f4 = xi4[c];
            b0 = dot2(wxi[4 * c + 0], xu.h[0], b0);
            b1 = dot2(wxi[4 * c + 1], xu.h[1], b1);
            b2 = dot2(wxi[4 * c + 2], xu.h[2], b2);
            b3 = dot2(wxi[4 * c + 3], xu.h[3], b3);
        }
#pragma unroll
        for (int c = 0; c < 16; ++c) {
            F4H hu; hu.f4 = hi4[c];
            b0 = dot2(whi[4 * c + 0], hu.h[0], b0);
            b1 = dot2(whi[4 * c + 1], hu.h[1], b1);
            b2 = dot2(whi[4 * c + 2], hu.h[2], b2);
            b3 = dot2(whi[4 * c + 3], hu.h[3], b3);
        }
        float acc2 = ((b0 + b1) + (b2 + b3)) + bi2;

        float ap2 = isT ? 2.f * acc2 : acc2;
        float s2  = __builtin_amdgcn_rcpf(1.f + __expf(-ap2));
        float av2 = isT ? fmaf(2.f, s2, -1.f) : s2;

        // state update inside the quad (no LDS, no barrier)
        float ii = qb<0>(av2), fi = qb<1>(av2), oi = qb<2>(av2), gg = qb<3>(av2);
        float cn_new = fmaf(fi, cn_reg, ii * gg);
        cn_reg = cn_new;
        float c_new = oi * tanh_f(cn_new);
        c_reg = c_new;
        float h_new = o_outer * tanh_f(c_new);

        float hn_n = rolN<4>(h_new);
        if ((j & 7) == 0) {
            f16x2 hp = pack2(h_new, hn_n);
            hb[u >> 1] = hp;
            if constexpr (!PROJ_IN)
                hrow[(size_t)t * (HH / 2) + (j >> 3)] = hp;  // h_t -> ws
        }
        // stash prefetched tile into the other buffer (last read pre-B_a)
        if (stl == 0) xt[tb ^ 1][xtl][xm] = pack2(pr0, pr1);
        barrier_lds();   // B_b: h_t (+ new tile) visible
    }

    // ---- final projection: out[S-1] from h_{S-1} (fallback mode only) ----
    if constexpr (PROJ_IN) {
        float p0 = 0.f, p1 = 0.f;
        F4H hu0; hu0.f4 = hb4[2 * ps];
        F4H hu1; hu1.f4 = hb4[2 * ps + 1];
        p0 = dot2(wl[0].h[0], hu0.h[0], p0);
        p1 = dot2(wl[0].h[1], hu0.h[1], p1);
        p0 = dot2(wl[0].h[2], hu0.h[2], p0);
        p1 = dot2(wl[0].h[3], hu0.h[3], p1);
        p0 = dot2(wl[1].h[0], hu1.h[0], p0);
        p1 = dot2(wl[1].h[1], hu1.h[1], p1);
        p0 = dot2(wl[1].h[2], hu1.h[2], p0);
        p1 = dot2(wl[1].h[3], hu1.h[3], p1);
        float p = p0 + p1;
        p += rolN<4>(p);
        p += rolN<2>(p);
        p += rolN<1>(p);
        if (ps == 0) orow[(size_t)(SS - 1) * OO + pn] = p + bl;
    }
}

// Post-scan projection: out[r, n] = h[r,:] @ W_lin[n,:] + b_lin[n].
// 512 blocks x 256 threads; wave = 64 lanes = all 64 output cols of one row
// (h row reads are wave-uniform global loads, served by L2/L3 since hws was
// just written). W_lin row n in registers; no LDS. 128 rows per wave.
__global__ void __launch_bounds__(256)
nlstm_proj(const f16x2* __restrict__ hws, const float* __restrict__ W_lin,
           const float* __restrict__ b_lin, float* __restrict__ out)
{
    const int n  = threadIdx.x & 63;   // output column
    const int rg = threadIdx.x >> 6;   // wave = row subgroup

    f16x2 wn[HH / 2];                  // W_lin row n, fp16 pairs (64 regs)
#pragma unroll
    for (int k = 0; k < HH / 2; ++k)
        wn[k] = pack2(W_lin[n * HH + 2 * k], W_lin[n * HH + 2 * k + 1]);
    const float bl = b_lin[n];

    const size_t r0 = (size_t)blockIdx.x * 512 + (size_t)rg * 128;
#pragma unroll 1
    for (int rr = 0; rr < 128; ++rr) {
        const size_t r = r0 + rr;
        const float4* hr = (const float4*)(hws + r * (HH / 2));
        float p0 = 0.f, p1 = 0.f, p2 = 0.f, p3 = 0.f;
#pragma unroll
        for (int c = 0; c < 16; ++c) {
            F4H hu; hu.f4 = hr[c];     // uniform across the wave
            p0 = dot2(wn[4 * c + 0], hu.h[0], p0);
            p1 = dot2(wn[4 * c + 1], hu.h[1], p1);
            p2 = dot2(wn[4 * c + 2], hu.h[2], p2);
            p3 = dot2(wn[4 * c + 3], hu.h[3], p3);
        }
        out[r * OO + n] = ((p0 + p1) + (p2 + p3)) + bl;
    }
}

extern "C" void kernel_launch(void* const* d_in, const int* in_sizes, int n_in,
                              void* d_out, int out_size, void* d_ws, size_t ws_size,
                              hipStream_t stream) {
    (void)in_sizes; (void)n_in; (void)out_size;
    const float* x      = (const float*)d_in[0];
    const float* Wx_out = (const float*)d_in[1];
    const float* Wh_out = (const float*)d_in[2];
    const float* b_out  = (const float*)d_in[3];
    const float* Wx_in  = (const float*)d_in[4];
    const float* Wh_in  = (const float*)d_in[5];
    const float* b_in   = (const float*)d_in[6];
    const float* W_lin  = (const float*)d_in[7];
    const float* b_lin  = (const float*)d_in[8];
    float* out = (float*)d_out;

    const size_t h_bytes = (size_t)BB * SS * (HH / 2) * sizeof(f16x2); // 64 MB
    if (d_ws != nullptr && ws_size >= h_bytes) {
        f16x2* hws = (f16x2*)d_ws;
        nlstm_scan<false><<<dim3(BB), dim3(512), 0, stream>>>(
            x, Wx_out, Wh_out, b_out, Wx_in, Wh_in, b_in, W_lin, b_lin,
            out, hws);
        nlstm_proj<<<dim3(512), dim3(256), 0, stream>>>(hws, W_lin, b_lin, out);
    } else {
        nlstm_scan<true><<<dim3(BB), dim3(512), 0, stream>>>(
            x, Wx_out, Wh_out, b_out, Wx_in, Wh_in, b_in, W_lin, b_lin,
            out, (f16x2*)nullptr);
    }
}

// Round 8
// 4061.718 us; speedup vs baseline: 3.6011x; 1.0101x over previous
//
#include <hip/hip_runtime.h>
#include <hip/hip_fp16.h>

#define BB 128
#define II 64
#define SS 2048
#define HH 128
#define GG 512   // 4*H
#define OO 64

typedef _Float16 f16x2 __attribute__((ext_vector_type(2)));
union F4H { float4 f4; f16x2 h[4]; };

__device__ __forceinline__ f16x2 pack2(float a, float b) {
    f16x2 r; r.x = (_Float16)a; r.y = (_Float16)b; return r;
}

__device__ __forceinline__ float dot2(f16x2 w, f16x2 v, float c) {
#if __has_builtin(__builtin_amdgcn_fdot2)
    return __builtin_amdgcn_fdot2(w, v, c, false);
#else
    return fmaf((float)w.x, (float)v.x, fmaf((float)w.y, (float)v.y, c));
#endif
}

__device__ __forceinline__ float tanh_f(float v) {
    float a = fabsf(v);
    float e = __expf(-2.0f * a);
    float r = (1.0f - e) * __builtin_amdgcn_rcpf(1.0f + e);
    return v < 0.0f ? -r : r;
}

// quad broadcast: every lane gets lane (quad_base + C)'s value. Pure-VALU DPP.
template<int C>
__device__ __forceinline__ float qb(float v) {
    return __int_as_float(__builtin_amdgcn_mov_dpp(
        __float_as_int(v), 0x55 * C, 0xF, 0xF, true));
}
// DPP row rotate-LEFT by N within each 16-lane row: lane i <- lane (i+N)&15.
// (row_ror:N gives lane i <- lane (i-N)&15 — that direction broke R2.)
template<int N>
__device__ __forceinline__ float rolN(float v) {
    return __int_as_float(__builtin_amdgcn_mov_dpp(
        __float_as_int(v), 0x120 + (16 - N), 0xF, 0xF, true));
}

// LDS-only barrier: avoids __syncthreads()'s vmcnt(0) drain of in-flight
// global loads/stores. LDS ordering (hb/xib/hib/xt) is all we need.
__device__ __forceinline__ void barrier_lds() {
    asm volatile("s_waitcnt lgkmcnt(0)\n\ts_barrier" ::: "memory");
}

// Time-parallel precompute (uses the 128 CUs the scan leaves idle, and runs
// at full occupancy): gates_x[b][t][j] = b_out[jcol] + x[b,:,t].Wx_out[:,jcol]
// stored PERMUTED by scan-thread index j so the scan's per-step load is a
// perfectly coalesced 4B(2B)/lane stream. Grid: 128 b x 16 time-chunks.
template<bool F32>
__global__ void __launch_bounds__(512)
nlstm_gatex(const float* __restrict__ x, const float* __restrict__ Wx_out,
            const float* __restrict__ b_out, void* __restrict__ gx)
{
    const int bb = blockIdx.x >> 4;        // batch element
    const int tc = blockIdx.x & 15;        // time chunk (128 steps)
    const int j  = threadIdx.x;
    const int u = j >> 2, g = j & 3;
    const int jcol = g * HH + u;

    // xs[tt][m] = (x[2m][T0+tt], x[2m+1][T0+tt]); row padded to 36 entries
    // (144B: 16B-aligned rows; write conflicts 8-way but one-time).
    __shared__ __align__(16) f16x2 xs[128][36];   // 18 KB

    f16x2 wxo[II / 2];                     // Wx_out col jcol (no pressure here)
#pragma unroll
    for (int m = 0; m < II / 2; ++m)
        wxo[m] = pack2(Wx_out[(2 * m) * GG + jcol],
                       Wx_out[(2 * m + 1) * GG + jcol]);
    const float bo = b_out[jcol];

    const float* xrow = x + (size_t)bb * II * SS;
    const int T0 = tc * 128;
#pragma unroll
    for (int r = 0; r < 8; ++r) {          // stage: coalesced along t
        const int idx = r * 512 + j;
        const int m = idx >> 7, tt = idx & 127;
        xs[tt][m] = pack2(xrow[(size_t)(2 * m) * SS + T0 + tt],
                          xrow[(size_t)(2 * m + 1) * SS + T0 + tt]);
    }
    __syncthreads();

#pragma unroll 1
    for (int tt = 0; tt < 128; ++tt) {
        const float4* xc4 = (const float4*)&xs[tt][0];
        float a0 = bo, a1 = 0.f, a2 = 0.f, a3 = 0.f;
#pragma unroll
        for (int c = 0; c < 8; ++c) {
            F4H xu; xu.f4 = xc4[c];        // broadcast read: conflict-free
            a0 = dot2(wxo[4 * c + 0], xu.h[0], a0);
            a1 = dot2(wxo[4 * c + 1], xu.h[1], a1);
            a2 = dot2(wxo[4 * c + 2], xu.h[2], a2);
            a3 = dot2(wxo[4 * c + 3], xu.h[3], a3);
        }
        const float v = (a0 + a1) + (a2 + a3);
        const size_t off = ((size_t)bb * SS + T0 + tt) * GG + j;  // coalesced
        if constexpr (F32) ((float*)gx)[off] = v;
        else               ((_Float16*)gx)[off] = (_Float16)v;
    }
}

// One block per batch element, 512 threads.
// Quad-gate layout: thread j owns gate column (j&3)*128 + (j>>2); gate
// combination and state update are DPP quad-broadcasts (no LDS/barrier).
// 2 raw (lgkm-only) barriers per step.
//
// REGISTER CLIFF (R4/R5/R6 lesson): this kernel sits exactly at the 256-reg
// unified VGPR/AGPR cap. ANY net-positive live-register change spills
// loop-resident values to L2-scratch (invisible in FETCH/WRITE!) ~2x cost.
// GX=0 loop body is byte-equivalent to R7's verified 4103 us version.
// R8: GX=1/2 -> x@Wx_out precomputed by nlstm_gatex (time-parallel);
// scan drops wxf (64KB LDS, 8 per-lane b128 reads/step), xt tiles and the
// x prefetch, replaced by one coalesced gx load/step prefetched 1 step
// ahead (register-NEGATIVE change).
template<int GX, bool PROJ_IN>   // GX: 0 none, 1 fp16 gx, 2 fp32 gx
__global__ void __launch_bounds__(512)
__attribute__((amdgpu_waves_per_eu(2)))
nlstm_scan(
    const float* __restrict__ x,
    const float* __restrict__ Wx_out, const float* __restrict__ Wh_out,
    const float* __restrict__ b_out,
    const float* __restrict__ Wx_in, const float* __restrict__ Wh_in,
    const float* __restrict__ b_in,
    const float* __restrict__ W_lin, const float* __restrict__ b_lin,
    float* __restrict__ out, f16x2* __restrict__ hws,
    const void* __restrict__ gxv)
{
    const int b = blockIdx.x;
    const int j = threadIdx.x;
    const int u = j >> 2;          // hidden unit
    const int g = j & 3;           // gate: 0=i 1=f 2=o 3=g
    const int jcol = g * HH + u;   // column of the 512-wide gate matrices

    __shared__ __align__(16) float4 wxf[GX == 0 ? 8 * 512 : 1];  // Wx_out fp16
    __shared__ __align__(16) f16x2 xt[GX == 0 ? 2 : 1][16][36];  // x tiles
    __shared__ __align__(16) f16x2 hb[HH / 2];         // h fp16
    __shared__ __align__(16) f16x2 xib[HH / 2];        // x_in fp16
    __shared__ __align__(16) f16x2 hib[HH / 2];        // h_in fp16

    // ---- register/AGPR-resident fp16 weights (column jcol): 192 regs ----
    f16x2 who[HH / 2];   // Wh_out col jcol
    f16x2 wxi[HH / 2];   // Wx_in  col jcol
    f16x2 whi[HH / 2];   // Wh_in  col jcol
#pragma unroll
    for (int m = 0; m < HH / 2; ++m)
        who[m] = pack2(Wh_out[(2 * m) * GG + jcol], Wh_out[(2 * m + 1) * GG + jcol]);
#pragma unroll
    for (int m = 0; m < HH / 2; ++m)
        wxi[m] = pack2(Wx_in[(2 * m) * GG + jcol], Wx_in[(2 * m + 1) * GG + jcol]);
#pragma unroll
    for (int m = 0; m < HH / 2; ++m)
        whi[m] = pack2(Wh_in[(2 * m) * GG + jcol], Wh_in[(2 * m + 1) * GG + jcol]);

    const float bo  = (GX == 0) ? b_out[j >> 0 ? jcol : jcol] : 0.f; // folded in gx when GX>0
    const float bi2 = b_in[jcol];

    // in-scan projection state (deep-fallback mode only)
    const int   pn = j >> 3;
    const int   ps = j & 7;
    float bl = 0.f;
    F4H wl[2];
    if constexpr (PROJ_IN) {
        bl = b_lin[pn];
#pragma unroll
        for (int q = 0; q < 2; ++q) {
            const int c = 2 * ps + q;
#pragma unroll
            for (int r = 0; r < 4; ++r)
                wl[q].h[r] = pack2(W_lin[pn * HH + 8 * c + 2 * r],
                                   W_lin[pn * HH + 8 * c + 2 * r + 1]);
        }
    }

    if constexpr (GX == 0) {
        // Wx_out column jcol -> LDS slot j, fp16 (lane-consecutive b128 reads)
#pragma unroll
        for (int c = 0; c < 8; ++c) {
            F4H w4;
#pragma unroll
            for (int q = 0; q < 4; ++q)
                w4.h[q] = pack2(Wx_out[(8 * c + 2 * q) * GG + jcol],
                                Wx_out[(8 * c + 2 * q + 1) * GG + jcol]);
            wxf[c * 512 + j] = w4.f4;
        }
    }

    const float* xrow = x + (size_t)b * II * SS;   // x[b,i,t] = xrow[i*SS + t]
    float* orow = out + (size_t)b * SS * OO;
    f16x2* hrow = hws + (size_t)b * SS * (HH / 2);  // wave-uniform -> SGPRs

    // x tile machinery (GX==0 only)
    const int xm  = j >> 4;    // 0..31
    const int xtl = j & 15;    // 0..15
    const float* xg0 = xrow + (size_t)(2 * xm) * SS + xtl;
    const float* xg1 = xrow + (size_t)(2 * xm + 1) * SS + xtl;

    // gx stream (GX>0): per-thread element, prefetched one step ahead
    const size_t gxbase = (size_t)b * SS * GG + j;
    const float*    gx32 = (const float*)gxv;
    const _Float16* gx16 = (const _Float16*)gxv;
    float gx_cur = 0.f;
    if constexpr (GX == 2) gx_cur = gx32[gxbase];
    else if constexpr (GX == 1) gx_cur = (float)gx16[gxbase];

    if constexpr (GX == 0)
        xt[0][xtl][xm] = pack2(xg0[0], xg1[0]);    // tile 0 -> buffer 0
    if (j < HH / 2) hb[j] = pack2(0.f, 0.f);
    __syncthreads();   // startup: full sync ok

    float c_reg = 0.f, cn_reg = 0.f;   // quad-replicated cell states (fp32)

    const float4* hb4 = (const float4*)hb;
    const float4* xi4 = (const float4*)xib;
    const float4* hi4 = (const float4*)hib;
    const bool isT = (g == 3);

    float pr0 = 0.f, pr1 = 0.f;        // x-tile prefetch registers (GX==0)

#pragma unroll 1
    for (int t = 0; t < SS; ++t) {
        const int stl = t & 15;        // step's row in the tile
        const int tb  = (t >> 4) & 1;  // current tile buffer

        // ---- prefetch next gx element / next x tile ----
        float gx_nxt = 0.f;
        if constexpr (GX != 0) {
            const int tn = (t + 1 < SS) ? t + 1 : t;   // clamp: dead reload
            if constexpr (GX == 2) gx_nxt = gx32[gxbase + (size_t)tn * GG];
            else                   gx_nxt = (float)gx16[gxbase + (size_t)tn * GG];
        } else if (stl == 0) {
            const int Tn = (t + 16 < SS) ? t + 16 : t;
            pr0 = xg0[Tn];
            pr1 = xg1[Tn];
        }

        // ---- outer gates: [x-part] + h@Wh_out, 4-way ILP ----
        float a0, a1 = 0.f, a2 = 0.f, a3 = 0.f;
        if constexpr (GX != 0) {
            a0 = gx_cur;                                // x-part + bias, precomputed
        } else {
            a0 = bo;
            const float4* xc4 = (const float4*)&xt[tb][stl][0];
#pragma unroll
            for (int c = 0; c < 8; ++c) {
                F4H xu; xu.f4 = xc4[c];
                F4H wu; wu.f4 = wxf[c * 512 + j];
                a0 = dot2(wu.h[0], xu.h[0], a0);
                a1 = dot2(wu.h[1], xu.h[1], a1);
                a2 = dot2(wu.h[2], xu.h[2], a2);
                a3 = dot2(wu.h[3], xu.h[3], a3);
            }
        }
#pragma unroll
        for (int c = 0; c < 16; ++c) {
            F4H hu; hu.f4 = hb4[c];
            a0 = dot2(who[4 * c + 0], hu.h[0], a0);
            a1 = dot2(who[4 * c + 1], hu.h[1], a1);
            a2 = dot2(who[4 * c + 2], hu.h[2], a2);
            a3 = dot2(who[4 * c + 3], hu.h[3], a3);
        }
        float acc = (a0 + a1) + (a2 + a3);

        // unified activation: g<3 sigmoid, g==3 tanh = 2*sigm(2x)-1
        float ap = isT ? 2.f * acc : acc;
        float s  = __builtin_amdgcn_rcpf(1.f + __expf(-ap));
        float av = isT ? fmaf(2.f, s, -1.f) : s;

        // gate combination inside the quad (no LDS, no barrier)
        float vi = qb<0>(av), vf = qb<1>(av), vo = qb<2>(av), vg = qb<3>(av);
        float x_in    = vi * vg;        // i * g
        float h_in    = vf * c_reg;     // f * c
        float o_outer = vo;             // kept for h_new

        // ---- in-scan projection of h_{t-1} (deep-fallback mode only) ----
        if constexpr (PROJ_IN) {
            float p0 = 0.f, p1 = 0.f;
            F4H hu0; hu0.f4 = hb4[2 * ps];
            F4H hu1; hu1.f4 = hb4[2 * ps + 1];
            p0 = dot2(wl[0].h[0], hu0.h[0], p0);
            p1 = dot2(wl[0].h[1], hu0.h[1], p1);
            p0 = dot2(wl[0].h[2], hu0.h[2], p0);
            p1 = dot2(wl[0].h[3], hu0.h[3], p1);
            p0 = dot2(wl[1].h[0], hu1.h[0], p0);
            p1 = dot2(wl[1].h[1], hu1.h[1], p1);
            p0 = dot2(wl[1].h[2], hu1.h[2], p0);
            p1 = dot2(wl[1].h[3], hu1.h[3], p1);
            float p = p0 + p1;
            p += rolN<4>(p);   // lane i += lane i+4 (ps==0 stays in-group)
            p += rolN<2>(p);
            p += rolN<1>(p);
            if (ps == 0 && t > 0) orow[(size_t)(t - 1) * OO + pn] = p + bl;
        }

        // write x_in/h_in pairs (lane j=8k packs units 2k,2k+1 via DPP rol4)
        float xin_n = rolN<4>(x_in);
        float hin_n = rolN<4>(h_in);
        if ((j & 7) == 0) {
            xib[u >> 1] = pack2(x_in, xin_n);
            hib[u >> 1] = pack2(h_in, hin_n);
        }
        barrier_lds();   // B_a: xib/hib visible; hb readers done before write

        // ---- inner gates: 4 shared accumulators (reg-minimal) ----
        float b0 = 0.f, b1 = 0.f, b2 = 0.f, b3 = 0.f;
#pragma unroll
        for (int c = 0; c < 16; ++c) {
            F4H xu; xu.f4 = xi4[c];
            b0 = dot2(wxi[4 * c + 0], xu.h[0], b0);
            b1 = dot2(wxi[4 * c + 1], xu.h[1], b1);
            b2 = dot2(wxi[4 * c + 2], xu.h[2], b2);
            b3 = dot2(wxi[4 * c + 3], xu.h[3], b3);
        }
#pragma unroll
        for (int c = 0; c < 16; ++c) {
            F4H hu; hu.f4 = hi4[c];
            b0 = dot2(whi[4 * c + 0], hu.h[0], b0);
            b1 = dot2(whi[4 * c + 1], hu.h[1], b1);
            b2 = dot2(whi[4 * c + 2], hu.h[2], b2);
            b3 = dot2(whi[4 * c + 3], hu.h[3], b3);
        }
        float acc2 = ((b0 + b1) + (b2 + b3)) + bi2;

        float ap2 = isT ? 2.f * acc2 : acc2;
        float s2  = __builtin_amdgcn_rcpf(1.f + __expf(-ap2));
        float av2 = isT ? fmaf(2.f, s2, -1.f) : s2;

        // state update inside the quad (no LDS, no barrier)
        float ii = qb<0>(av2), fi = qb<1>(av2), oi = qb<2>(av2), gg = qb<3>(av2);
        float cn_new = fmaf(fi, cn_reg, ii * gg);
        cn_reg = cn_new;
        float c_new = oi * tanh_f(cn_new);
        c_reg = c_new;
        float h_new = o_outer * tanh_f(c_new);

        float hn_n = rolN<4>(h_new);
        if ((j & 7) == 0) {
            f16x2 hp = pack2(h_new, hn_n);
            hb[u >> 1] = hp;
            if constexpr (!PROJ_IN)
                hrow[(size_t)t * (HH / 2) + (j >> 3)] = hp;  // h_t -> ws
        }
        if constexpr (GX == 0)
            if (stl == 0) xt[tb ^ 1][xtl][xm] = pack2(pr0, pr1);
        if constexpr (GX != 0) gx_cur = gx_nxt;
        barrier_lds();   // B_b: h_t (+ new tile) visible
    }

    // ---- final projection: out[S-1] from h_{S-1} (deep-fallback only) ----
    if constexpr (PROJ_IN) {
        float p0 = 0.f, p1 = 0.f;
        F4H hu0; hu0.f4 = hb4[2 * ps];
        F4H hu1; hu1.f4 = hb4[2 * ps + 1];
        p0 = dot2(wl[0].h[0], hu0.h[0], p0);
        p1 = dot2(wl[0].h[1], hu0.h[1], p1);
        p0 = dot2(wl[0].h[2], hu0.h[2], p0);
        p1 = dot2(wl[0].h[3], hu0.h[3], p1);
        p0 = dot2(wl[1].h[0], hu1.h[0], p0);
        p1 = dot2(wl[1].h[1], hu1.h[1], p1);
        p0 = dot2(wl[1].h[2], hu1.h[2], p0);
        p1 = dot2(wl[1].h[3], hu1.h[3], p1);
        float p = p0 + p1;
        p += rolN<4>(p);
        p += rolN<2>(p);
        p += rolN<1>(p);
        if (ps == 0) orow[(size_t)(SS - 1) * OO + pn] = p + bl;
    }
}

// Post-scan projection: out[r, n] = h[r,:] @ W_lin[n,:] + b_lin[n].
// 512 blocks x 256 threads; wave = 64 lanes = all 64 output cols of one row
// (h row reads are wave-uniform global loads). W_lin row n in registers.
__global__ void __launch_bounds__(256)
nlstm_proj(const f16x2* __restrict__ hws, const float* __restrict__ W_lin,
           const float* __restrict__ b_lin, float* __restrict__ out)
{
    const int n  = threadIdx.x & 63;   // output column
    const int rg = threadIdx.x >> 6;   // wave = row subgroup

    f16x2 wn[HH / 2];                  // W_lin row n, fp16 pairs
#pragma unroll
    for (int k = 0; k < HH / 2; ++k)
        wn[k] = pack2(W_lin[n * HH + 2 * k], W_lin[n * HH + 2 * k + 1]);
    const float bl = b_lin[n];

    const size_t r0 = (size_t)blockIdx.x * 512 + (size_t)rg * 128;
#pragma unroll 1
    for (int rr = 0; rr < 128; ++rr) {
        const size_t r = r0 + rr;
        const float4* hr = (const float4*)(hws + r * (HH / 2));
        float p0 = 0.f, p1 = 0.f, p2 = 0.f, p3 = 0.f;
#pragma unroll
        for (int c = 0; c < 16; ++c) {
            F4H hu; hu.f4 = hr[c];     // uniform across the wave
            p0 = dot2(wn[4 * c + 0], hu.h[0], p0);
            p1 = dot2(wn[4 * c + 1], hu.h[1], p1);
            p2 = dot2(wn[4 * c + 2], hu.h[2], p2);
            p3 = dot2(wn[4 * c + 3], hu.h[3], p3);
        }
        out[r * OO + n] = ((p0 + p1) + (p2 + p3)) + bl;
    }
}

extern "C" void kernel_launch(void* const* d_in, const int* in_sizes, int n_in,
                              void* d_out, int out_size, void* d_ws, size_t ws_size,
                              hipStream_t stream) {
    (void)in_sizes; (void)n_in; (void)out_size;
    const float* x      = (const float*)d_in[0];
    const float* Wx_out = (const float*)d_in[1];
    const float* Wh_out = (const float*)d_in[2];
    const float* b_out  = (const float*)d_in[3];
    const float* Wx_in  = (const float*)d_in[4];
    const float* Wh_in  = (const float*)d_in[5];
    const float* b_in   = (const float*)d_in[6];
    const float* W_lin  = (const float*)d_in[7];
    const float* b_lin  = (const float*)d_in[8];
    float* out = (float*)d_out;

    const size_t h_bytes  = (size_t)BB * SS * (HH / 2) * sizeof(f16x2); // 64 MB
    const size_t gx_elems = (size_t)BB * SS * GG;
    const size_t gx32_b   = gx_elems * 4;   // 512 MB
    const size_t gx16_b   = gx_elems * 2;   // 256 MB

    if (d_ws != nullptr && ws_size >= h_bytes + gx32_b) {
        // Tier A: fp32 gates_x
        f16x2* hws = (f16x2*)d_ws;
        void* gx = (void*)((char*)d_ws + h_bytes);
        nlstm_gatex<true><<<dim3(BB * 16), dim3(512), 0, stream>>>(
            x, Wx_out, b_out, gx);
        nlstm_scan<2, false><<<dim3(BB), dim3(512), 0, stream>>>(
            x, Wx_out, Wh_out, b_out, Wx_in, Wh_in, b_in, W_lin, b_lin,
            out, hws, gx);
        nlstm_proj<<<dim3(512), dim3(256), 0, stream>>>(hws, W_lin, b_lin, out);
    } else if (d_ws != nullptr && ws_size >= h_bytes + gx16_b) {
        // Tier B: fp16 gates_x
        f16x2* hws = (f16x2*)d_ws;
        void* gx = (void*)((char*)d_ws + h_bytes);
        nlstm_gatex<false><<<dim3(BB * 16), dim3(512), 0, stream>>>(
            x, Wx_out, b_out, gx);
        nlstm_scan<1, false><<<dim3(BB), dim3(512), 0, stream>>>(
            x, Wx_out, Wh_out, b_out, Wx_in, Wh_in, b_in, W_lin, b_lin,
            out, hws, gx);
        nlstm_proj<<<dim3(512), dim3(256), 0, stream>>>(hws, W_lin, b_lin, out);
    } else if (d_ws != nullptr && ws_size >= h_bytes) {
        // Tier C: R7 path (x staged in scan, proj hoisted)
        f16x2* hws = (f16x2*)d_ws;
        nlstm_scan<0, false><<<dim3(BB), dim3(512), 0, stream>>>(
            x, Wx_out, Wh_out, b_out, Wx_in, Wh_in, b_in, W_lin, b_lin,
            out, hws, nullptr);
        nlstm_proj<<<dim3(512), dim3(256), 0, stream>>>(hws, W_lin, b_lin, out);
    } else {
        // Tier D: fully fused fallback (R3 path)
        nlstm_scan<0, true><<<dim3(BB), dim3(512), 0, stream>>>(
            x, Wx_out, Wh_out, b_out, Wx_in, Wh_in, b_in, W_lin, b_lin,
            out, (f16x2*)nullptr, nullptr);
    }
}

// Round 9
// 3841.341 us; speedup vs baseline: 3.8076x; 1.0574x over previous
//
#include <hip/hip_runtime.h>
#include <hip/hip_fp16.h>

#define BB 128
#define II 64
#define SS 2048
#define HH 128
#define GG 512   // 4*H
#define OO 64

typedef _Float16 f16x2 __attribute__((ext_vector_type(2)));
union F4H { float4 f4; f16x2 h[4]; };

__device__ __forceinline__ f16x2 pack2(float a, float b) {
    f16x2 r; r.x = (_Float16)a; r.y = (_Float16)b; return r;
}

__device__ __forceinline__ float dot2(f16x2 w, f16x2 v, float c) {
#if __has_builtin(__builtin_amdgcn_fdot2)
    return __builtin_amdgcn_fdot2(w, v, c, false);
#else
    return fmaf((float)w.x, (float)v.x, fmaf((float)w.y, (float)v.y, c));
#endif
}

__device__ __forceinline__ float tanh_f(float v) {
    float a = fabsf(v);
    float e = __expf(-2.0f * a);
    float r = (1.0f - e) * __builtin_amdgcn_rcpf(1.0f + e);
    return v < 0.0f ? -r : r;
}

// quad broadcast: every lane gets lane (quad_base + C)'s value. Pure-VALU DPP.
template<int C>
__device__ __forceinline__ float qb(float v) {
    return __int_as_float(__builtin_amdgcn_mov_dpp(
        __float_as_int(v), 0x55 * C, 0xF, 0xF, true));
}
// DPP row rotate-LEFT by N within each 16-lane row: lane i <- lane (i+N)&15.
// (row_ror:N gives lane i <- lane (i-N)&15 — that direction broke R2.)
template<int N>
__device__ __forceinline__ float rolN(float v) {
    return __int_as_float(__builtin_amdgcn_mov_dpp(
        __float_as_int(v), 0x120 + (16 - N), 0xF, 0xF, true));
}

// LDS-only barrier: avoids __syncthreads()'s vmcnt(0) drain of in-flight
// global loads/stores. LDS ordering (hb/xib/hib) is all we need.
__device__ __forceinline__ void barrier_lds() {
    asm volatile("s_waitcnt lgkmcnt(0)\n\ts_barrier" ::: "memory");
}

// ---------------------------------------------------------------------------
// Time-parallel precompute: gx[bb][tl][j] = b_out[jcol] + x[bb,:,T]·Wx_out[:,jcol]
// for T in [t0, t0 + nchunk*128), stored chunk-local and PERMUTED by scan
// thread index j (scan's per-step load = coalesced 4B/lane stream).
// Grid: BB * nchunk blocks of 512. Runs at full GPU occupancy.
__global__ void __launch_bounds__(512)
nlstm_gatex(const float* __restrict__ x, const float* __restrict__ Wx_out,
            const float* __restrict__ b_out, float* __restrict__ gx,
            int t0, int nchunk)
{
    const int bb  = blockIdx.x / nchunk;
    const int tcw = blockIdx.x % nchunk;
    const int j   = threadIdx.x;
    const int u = j >> 2, g = j & 3;
    const int jcol = g * HH + u;

    // xs[tt][m] = (x[2m][T0+tt], x[2m+1][T0+tt]); row padded to 36 entries
    // (144B rows, 16B aligned; staging write 8-way conflict but one-time).
    __shared__ __align__(16) f16x2 xs[128][36];   // 18.4 KB

    f16x2 wxo[II / 2];                     // Wx_out col jcol
#pragma unroll
    for (int m = 0; m < II / 2; ++m)
        wxo[m] = pack2(Wx_out[(2 * m) * GG + jcol],
                       Wx_out[(2 * m + 1) * GG + jcol]);
    const float bo = b_out[jcol];

    const float* xrow = x + (size_t)bb * II * SS;
    const int T0 = t0 + tcw * 128;
#pragma unroll
    for (int r = 0; r < 8; ++r) {          // stage: coalesced along t
        const int idx = r * 512 + j;
        const int m = idx >> 7, tt = idx & 127;
        xs[tt][m] = pack2(xrow[(size_t)(2 * m) * SS + T0 + tt],
                          xrow[(size_t)(2 * m + 1) * SS + T0 + tt]);
    }
    __syncthreads();

#pragma unroll 1
    for (int tt = 0; tt < 128; ++tt) {
        const float4* xc4 = (const float4*)&xs[tt][0];
        float a0 = bo, a1 = 0.f, a2 = 0.f, a3 = 0.f;
#pragma unroll
        for (int c = 0; c < 8; ++c) {
            F4H xu; xu.f4 = xc4[c];        // broadcast read: conflict-free
            a0 = dot2(wxo[4 * c + 0], xu.h[0], a0);
            a1 = dot2(wxo[4 * c + 1], xu.h[1], a1);
            a2 = dot2(wxo[4 * c + 2], xu.h[2], a2);
            a3 = dot2(wxo[4 * c + 3], xu.h[3], a3);
        }
        const float v = (a0 + a1) + (a2 + a3);
        const size_t tl = (size_t)tcw * 128 + tt;          // chunk-local t
        gx[((size_t)bb * nchunk * 128 + tl) * GG + j] = v; // coalesced
    }
}

// ---------------------------------------------------------------------------
// Segmented scan: processes t in [t0, t1) reading precomputed gx (chunk-local
// [BB][Tc][GG] fp32). State (h, c, cn) persisted in hst/cst/cnst across
// segments. Body = R7's verified loop minus the whole x path (no wxf 64KB
// LDS, no per-lane b128 weight reads, no xt tiles) — register-NEGATIVE.
//
// REGISTER CLIFF (R4/R5/R6): any net-positive live-register change spills
// loop-resident values to L2-scratch (~2x cost, invisible in FETCH/WRITE).
template<bool PROJ_IN>
__global__ void __launch_bounds__(512)
__attribute__((amdgpu_waves_per_eu(2)))
nlstm_scan_seg(
    const float* __restrict__ Wh_out,
    const float* __restrict__ Wx_in, const float* __restrict__ Wh_in,
    const float* __restrict__ b_in,
    const float* __restrict__ W_lin, const float* __restrict__ b_lin,
    const float* __restrict__ gx, float* __restrict__ out,
    f16x2* __restrict__ hws, f16x2* __restrict__ hst,
    float* __restrict__ cst, float* __restrict__ cnst,
    int t0, int t1, int Tc)
{
    const int b = blockIdx.x;
    const int j = threadIdx.x;
    const int u = j >> 2;          // hidden unit
    const int g = j & 3;           // gate: 0=i 1=f 2=o 3=g
    const int jcol = g * HH + u;   // column of the 512-wide gate matrices

    __shared__ __align__(16) f16x2 hb[HH / 2];         // h fp16
    __shared__ __align__(16) f16x2 xib[HH / 2];        // x_in fp16
    __shared__ __align__(16) f16x2 hib[HH / 2];        // h_in fp16

    // ---- register/AGPR-resident fp16 weights (column jcol): 192 regs ----
    f16x2 who[HH / 2];   // Wh_out col jcol
    f16x2 wxi[HH / 2];   // Wx_in  col jcol
    f16x2 whi[HH / 2];   // Wh_in  col jcol
#pragma unroll
    for (int m = 0; m < HH / 2; ++m)
        who[m] = pack2(Wh_out[(2 * m) * GG + jcol], Wh_out[(2 * m + 1) * GG + jcol]);
#pragma unroll
    for (int m = 0; m < HH / 2; ++m)
        wxi[m] = pack2(Wx_in[(2 * m) * GG + jcol], Wx_in[(2 * m + 1) * GG + jcol]);
#pragma unroll
    for (int m = 0; m < HH / 2; ++m)
        whi[m] = pack2(Wh_in[(2 * m) * GG + jcol], Wh_in[(2 * m + 1) * GG + jcol]);

    const float bi2 = b_in[jcol];

    // in-scan projection state (PROJ_IN mode)
    const int   pn = j >> 3;
    const int   ps = j & 7;
    float bl = 0.f;
    F4H wl[2];
    if constexpr (PROJ_IN) {
        bl = b_lin[pn];
#pragma unroll
        for (int q = 0; q < 2; ++q) {
            const int c = 2 * ps + q;
#pragma unroll
            for (int r = 0; r < 4; ++r)
                wl[q].h[r] = pack2(W_lin[pn * HH + 8 * c + 2 * r],
                                   W_lin[pn * HH + 8 * c + 2 * r + 1]);
        }
    }

    float* orow = out + (size_t)b * SS * OO;
    f16x2* hrow = (PROJ_IN ? (f16x2*)nullptr : hws + (size_t)b * SS * (HH / 2));
    const float* gxrow = gx + (size_t)b * Tc * GG;   // chunk-local stream

    // ---- state load ----
    float c_reg, cn_reg;
    if (t0 == 0) {
        if (j < HH / 2) hb[j] = pack2(0.f, 0.f);
        c_reg = 0.f; cn_reg = 0.f;
    } else {
        if (j < HH / 2) hb[j] = hst[b * (HH / 2) + j];
        c_reg  = cst[b * HH + u];    // quad lanes read same addr (broadcast)
        cn_reg = cnst[b * HH + u];
    }
    __syncthreads();   // startup: full sync ok

    const float4* hb4 = (const float4*)hb;
    const float4* xi4 = (const float4*)xib;
    const float4* hi4 = (const float4*)hib;
    const bool isT = (g == 3);

    float gx_cur = gxrow[j];   // tl = 0, prefetched stream

#pragma unroll 1
    for (int t = t0; t < t1; ++t) {
        const int tl = t - t0;

        // ---- prefetch next gx element (coalesced 4B/lane) ----
        const int tln = (tl + 1 < Tc) ? tl + 1 : tl;   // clamp: dead reload
        const float gx_nxt = gxrow[(size_t)tln * GG + j];

        // ---- outer gates: gx (precomputed x-part + bias) + h@Wh_out ----
        float a0 = gx_cur, a1 = 0.f, a2 = 0.f, a3 = 0.f;
#pragma unroll
        for (int c = 0; c < 16; ++c) {
            F4H hu; hu.f4 = hb4[c];
            a0 = dot2(who[4 * c + 0], hu.h[0], a0);
            a1 = dot2(who[4 * c + 1], hu.h[1], a1);
            a2 = dot2(who[4 * c + 2], hu.h[2], a2);
            a3 = dot2(who[4 * c + 3], hu.h[3], a3);
        }
        float acc = (a0 + a1) + (a2 + a3);

        // unified activation: g<3 sigmoid, g==3 tanh = 2*sigm(2x)-1
        float ap = isT ? 2.f * acc : acc;
        float s  = __builtin_amdgcn_rcpf(1.f + __expf(-ap));
        float av = isT ? fmaf(2.f, s, -1.f) : s;

        // gate combination inside the quad (no LDS, no barrier)
        float vi = qb<0>(av), vf = qb<1>(av), vo = qb<2>(av), vg = qb<3>(av);
        float x_in    = vi * vg;        // i * g
        float h_in    = vf * c_reg;     // f * c
        float o_outer = vo;             // kept for h_new

        // ---- in-scan projection of h_{t-1} (PROJ_IN mode) ----
        if constexpr (PROJ_IN) {
            float p0 = 0.f, p1 = 0.f;
            F4H hu0; hu0.f4 = hb4[2 * ps];
            F4H hu1; hu1.f4 = hb4[2 * ps + 1];
            p0 = dot2(wl[0].h[0], hu0.h[0], p0);
            p1 = dot2(wl[0].h[1], hu0.h[1], p1);
            p0 = dot2(wl[0].h[2], hu0.h[2], p0);
            p1 = dot2(wl[0].h[3], hu0.h[3], p1);
            p0 = dot2(wl[1].h[0], hu1.h[0], p0);
            p1 = dot2(wl[1].h[1], hu1.h[1], p1);
            p0 = dot2(wl[1].h[2], hu1.h[2], p0);
            p1 = dot2(wl[1].h[3], hu1.h[3], p1);
            float p = p0 + p1;
            p += rolN<4>(p);   // lane i += lane i+4 (ps==0 stays in-group)
            p += rolN<2>(p);
            p += rolN<1>(p);
            if (ps == 0 && t > 0) orow[(size_t)(t - 1) * OO + pn] = p + bl;
        }

        // write x_in/h_in pairs (lane j=8k packs units 2k,2k+1 via DPP rol4)
        float xin_n = rolN<4>(x_in);
        float hin_n = rolN<4>(h_in);
        if ((j & 7) == 0) {
            xib[u >> 1] = pack2(x_in, xin_n);
            hib[u >> 1] = pack2(h_in, hin_n);
        }
        barrier_lds();   // B_a: xib/hib visible; hb readers done before write

        // ---- inner gates: 4 shared accumulators (reg-minimal) ----
        float b0 = 0.f, b1 = 0.f, b2 = 0.f, b3 = 0.f;
#pragma unroll
        for (int c = 0; c < 16; ++c) {
            F4H xu; xu.f4 = xi4[c];
            b0 = dot2(wxi[4 * c + 0], xu.h[0], b0);
            b1 = dot2(wxi[4 * c + 1], xu.h[1], b1);
            b2 = dot2(wxi[4 * c + 2], xu.h[2], b2);
            b3 = dot2(wxi[4 * c + 3], xu.h[3], b3);
        }
#pragma unroll
        for (int c = 0; c < 16; ++c) {
            F4H hu; hu.f4 = hi4[c];
            b0 = dot2(whi[4 * c + 0], hu.h[0], b0);
            b1 = dot2(whi[4 * c + 1], hu.h[1], b1);
            b2 = dot2(whi[4 * c + 2], hu.h[2], b2);
            b3 = dot2(whi[4 * c + 3], hu.h[3], b3);
        }
        float acc2 = ((b0 + b1) + (b2 + b3)) + bi2;

        float ap2 = isT ? 2.f * acc2 : acc2;
        float s2  = __builtin_amdgcn_rcpf(1.f + __expf(-ap2));
        float av2 = isT ? fmaf(2.f, s2, -1.f) : s2;

        // state update inside the quad (no LDS, no barrier)
        float ii = qb<0>(av2), fi = qb<1>(av2), oi = qb<2>(av2), gg = qb<3>(av2);
        float cn_new = fmaf(fi, cn_reg, ii * gg);
        cn_reg = cn_new;
        float c_new = oi * tanh_f(cn_new);
        c_reg = c_new;
        float h_new = o_outer * tanh_f(c_new);

        float hn_n = rolN<4>(h_new);
        if ((j & 7) == 0) {
            f16x2 hp = pack2(h_new, hn_n);
            hb[u >> 1] = hp;
            if constexpr (!PROJ_IN)
                hrow[(size_t)t * (HH / 2) + (j >> 3)] = hp;  // h_t -> ws
        }
        gx_cur = gx_nxt;
        barrier_lds();   // B_b: h_t visible
    }

    // ---- state save (hb stable after final B_b) ----
    if (j < HH / 2) hst[b * (HH / 2) + j] = hb[j];
    if (g == 0) { cst[b * HH + u] = c_reg; cnst[b * HH + u] = cn_reg; }

    // ---- final projection: out[S-1] (PROJ_IN mode, last segment only) ----
    if constexpr (PROJ_IN) {
        if (t1 == SS) {
            float p0 = 0.f, p1 = 0.f;
            F4H hu0; hu0.f4 = hb4[2 * ps];
            F4H hu1; hu1.f4 = hb4[2 * ps + 1];
            p0 = dot2(wl[0].h[0], hu0.h[0], p0);
            p1 = dot2(wl[0].h[1], hu0.h[1], p1);
            p0 = dot2(wl[0].h[2], hu0.h[2], p0);
            p1 = dot2(wl[0].h[3], hu0.h[3], p1);
            p0 = dot2(wl[1].h[0], hu1.h[0], p0);
            p1 = dot2(wl[1].h[1], hu1.h[1], p1);
            p0 = dot2(wl[1].h[2], hu1.h[2], p0);
            p1 = dot2(wl[1].h[3], hu1.h[3], p1);
            float p = p0 + p1;
            p += rolN<4>(p);
            p += rolN<2>(p);
            p += rolN<1>(p);
            if (ps == 0) orow[(size_t)(SS - 1) * OO + pn] = p + bl;
        }
    }
}

// ---------------------------------------------------------------------------
// Fully fused fallback (R3/R7-verified path): x staged in-scan, in-scan proj.
__global__ void __launch_bounds__(512)
__attribute__((amdgpu_waves_per_eu(2)))
nlstm_fused(
    const float* __restrict__ x,
    const float* __restrict__ Wx_out, const float* __restrict__ Wh_out,
    const float* __restrict__ b_out,
    const float* __restrict__ Wx_in, const float* __restrict__ Wh_in,
    const float* __restrict__ b_in,
    const float* __restrict__ W_lin, const float* __restrict__ b_lin,
    float* __restrict__ out)
{
    const int b = blockIdx.x;
    const int j = threadIdx.x;
    const int u = j >> 2, g = j & 3;
    const int jcol = g * HH + u;

    __shared__ __align__(16) float4 wxf[8 * 512];
    __shared__ __align__(16) f16x2 xt[2][16][36];
    __shared__ __align__(16) f16x2 hb[HH / 2];
    __shared__ __align__(16) f16x2 xib[HH / 2];
    __shared__ __align__(16) f16x2 hib[HH / 2];

    f16x2 who[HH / 2], wxi[HH / 2], whi[HH / 2];
#pragma unroll
    for (int m = 0; m < HH / 2; ++m)
        who[m] = pack2(Wh_out[(2 * m) * GG + jcol], Wh_out[(2 * m + 1) * GG + jcol]);
#pragma unroll
    for (int m = 0; m < HH / 2; ++m)
        wxi[m] = pack2(Wx_in[(2 * m) * GG + jcol], Wx_in[(2 * m + 1) * GG + jcol]);
#pragma unroll
    for (int m = 0; m < HH / 2; ++m)
        whi[m] = pack2(Wh_in[(2 * m) * GG + jcol], Wh_in[(2 * m + 1) * GG + jcol]);

    const float bo = b_out[jcol];
    const float bi2 = b_in[jcol];
    const int pn = j >> 3, ps = j & 7;
    const float bl = b_lin[pn];
    F4H wl[2];
#pragma unroll
    for (int q = 0; q < 2; ++q) {
        const int c = 2 * ps + q;
#pragma unroll
        for (int r = 0; r < 4; ++r)
            wl[q].h[r] = pack2(W_lin[pn * HH + 8 * c + 2 * r],
                               W_lin[pn * HH + 8 * c + 2 * r + 1]);
    }
#pragma unroll
    for (int c = 0; c < 8; ++c) {
        F4H w4;
#pragma unroll
        for (int q = 0; q < 4; ++q)
            w4.h[q] = pack2(Wx_out[(8 * c + 2 * q) * GG + jcol],
                            Wx_out[(8 * c + 2 * q + 1) * GG + jcol]);
        wxf[c * 512 + j] = w4.f4;
    }

    const float* xrow = x + (size_t)b * II * SS;
    float* orow = out + (size_t)b * SS * OO;
    const int xm = j >> 4, xtl = j & 15;
    const float* xg0 = xrow + (size_t)(2 * xm) * SS + xtl;
    const float* xg1 = xrow + (size_t)(2 * xm + 1) * SS + xtl;

    xt[0][xtl][xm] = pack2(xg0[0], xg1[0]);
    if (j < HH / 2) hb[j] = pack2(0.f, 0.f);
    __syncthreads();

    float c_reg = 0.f, cn_reg = 0.f;
    const float4* hb4 = (const float4*)hb;
    const float4* xi4 = (const float4*)xib;
    const float4* hi4 = (const float4*)hib;
    const bool isT = (g == 3);
    float pr0 = 0.f, pr1 = 0.f;

#pragma unroll 1
    for (int t = 0; t < SS; ++t) {
        const int stl = t & 15;
        const int tb = (t >> 4) & 1;
        if (stl == 0) {
            const int Tn = (t + 16 < SS) ? t + 16 : t;
            pr0 = xg0[Tn];
            pr1 = xg1[Tn];
        }
        const float4* xc4 = (const float4*)&xt[tb][stl][0];
        float a0 = bo, a1 = 0.f, a2 = 0.f, a3 = 0.f;
#pragma unroll
        for (int c = 0; c < 8; ++c) {
            F4H xu; xu.f4 = xc4[c];
            F4H wu; wu.f4 = wxf[c * 512 + j];
            a0 = dot2(wu.h[0], xu.h[0], a0);
            a1 = dot2(wu.h[1], xu.h[1], a1);
            a2 = dot2(wu.h[2], xu.h[2], a2);
            a3 = dot2(wu.h[3], xu.h[3], a3);
        }
#pragma unroll
        for (int c = 0; c < 16; ++c) {
            F4H hu; hu.f4 = hb4[c];
            a0 = dot2(who[4 * c + 0], hu.h[0], a0);
            a1 = dot2(who[4 * c + 1], hu.h[1], a1);
            a2 = dot2(who[4 * c + 2], hu.h[2], a2);
            a3 = dot2(who[4 * c + 3], hu.h[3], a3);
        }
        float acc = (a0 + a1) + (a2 + a3);
        float ap = isT ? 2.f * acc : acc;
        float s = __builtin_amdgcn_rcpf(1.f + __expf(-ap));
        float av = isT ? fmaf(2.f, s, -1.f) : s;
        float vi = qb<0>(av), vf = qb<1>(av), vo = qb<2>(av), vg = qb<3>(av);
        float x_in = vi * vg, h_in = vf * c_reg, o_outer = vo;

        float p0 = 0.f, p1 = 0.f;
        {
            F4H hu0; hu0.f4 = hb4[2 * ps];
            F4H hu1; hu1.f4 = hb4[2 * ps + 1];
            p0 = dot2(wl[0].h[0], hu0.h[0], p0);
            p1 = dot2(wl[0].h[1], hu0.h[1], p1);
            p0 = dot2(wl[0].h[2], hu0.h[2], p0);
            p1 = dot2(wl[0].h[3], hu0.h[3], p1);
            p0 = dot2(wl[1].h[0], hu1.h[0], p0);
            p1 = dot2(wl[1].h[1], hu1.h[1], p1);
            p0 = dot2(wl[1].h[2], hu1.h[2], p0);
            p1 = dot2(wl[1].h[3], hu1.h[3], p1);
        }
        float p = p0 + p1;
        p += rolN<4>(p);
        p += rolN<2>(p);
        p += rolN<1>(p);
        if (ps == 0 && t > 0) orow[(size_t)(t - 1) * OO + pn] = p + bl;

        float xin_n = rolN<4>(x_in);
        float hin_n = rolN<4>(h_in);
        if ((j & 7) == 0) {
            xib[u >> 1] = pack2(x_in, xin_n);
            hib[u >> 1] = pack2(h_in, hin_n);
        }
        barrier_lds();

        float b0 = 0.f, b1 = 0.f, b2 = 0.f, b3 = 0.f;
#pragma unroll
        for (int c = 0; c < 16; ++c) {
            F4H xu; xu.f4 = xi4[c];
            b0 = dot2(wxi[4 * c + 0], xu.h[0], b0);
            b1 = dot2(wxi[4 * c + 1], xu.h[1], b1);
            b2 = dot2(wxi[4 * c + 2], xu.h[2], b2);
            b3 = dot2(wxi[4 * c + 3], xu.h[3], b3);
        }
#pragma unroll
        for (int c = 0; c < 16; ++c) {
            F4H hu; hu.f4 = hi4[c];
            b0 = dot2(whi[4 * c + 0], hu.h[0], b0);
            b1 = dot2(whi[4 * c + 1], hu.h[1], b1);
            b2 = dot2(whi[4 * c + 2], hu.h[2], b2);
            b3 = dot2(whi[4 * c + 3], hu.h[3], b3);
        }
        float acc2 = ((b0 + b1) + (b2 + b3)) + bi2;
        float ap2 = isT ? 2.f * acc2 : acc2;
        float s2 = __builtin_amdgcn_rcpf(1.f + __expf(-ap2));
        float av2 = isT ? fmaf(2.f, s2, -1.f) : s2;
        float ii = qb<0>(av2), fi = qb<1>(av2), oi = qb<2>(av2), gg = qb<3>(av2);
        float cn_new = fmaf(fi, cn_reg, ii * gg);
        cn_reg = cn_new;
        float c_new = oi * tanh_f(cn_new);
        c_reg = c_new;
        float h_new = o_outer * tanh_f(c_new);
        float hn_n = rolN<4>(h_new);
        if ((j & 7) == 0) hb[u >> 1] = pack2(h_new, hn_n);
        if (stl == 0) xt[tb ^ 1][xtl][xm] = pack2(pr0, pr1);
        barrier_lds();
    }
    {
        float p0 = 0.f, p1 = 0.f;
        F4H hu0; hu0.f4 = hb4[2 * ps];
        F4H hu1; hu1.f4 = hb4[2 * ps + 1];
        p0 = dot2(wl[0].h[0], hu0.h[0], p0);
        p1 = dot2(wl[0].h[1], hu0.h[1], p1);
        p0 = dot2(wl[0].h[2], hu0.h[2], p0);
        p1 = dot2(wl[0].h[3], hu0.h[3], p1);
        p0 = dot2(wl[1].h[0], hu1.h[0], p0);
        p1 = dot2(wl[1].h[1], hu1.h[1], p1);
        p0 = dot2(wl[1].h[2], hu1.h[2], p0);
        p1 = dot2(wl[1].h[3], hu1.h[3], p1);
        float p = p0 + p1;
        p += rolN<4>(p);
        p += rolN<2>(p);
        p += rolN<1>(p);
        if (ps == 0) orow[(size_t)(SS - 1) * OO + pn] = p + bl;
    }
}

// Post-scan projection: out[r, n] = h[r,:] @ W_lin[n,:] + b_lin[n].
__global__ void __launch_bounds__(256)
nlstm_proj(const f16x2* __restrict__ hws, const float* __restrict__ W_lin,
           const float* __restrict__ b_lin, float* __restrict__ out)
{
    const int n  = threadIdx.x & 63;
    const int rg = threadIdx.x >> 6;

    f16x2 wn[HH / 2];
#pragma unroll
    for (int k = 0; k < HH / 2; ++k)
        wn[k] = pack2(W_lin[n * HH + 2 * k], W_lin[n * HH + 2 * k + 1]);
    const float bl = b_lin[n];

    const size_t r0 = (size_t)blockIdx.x * 512 + (size_t)rg * 128;
#pragma unroll 1
    for (int rr = 0; rr < 128; ++rr) {
        const size_t r = r0 + rr;
        const float4* hr = (const float4*)(hws + r * (HH / 2));
        float p0 = 0.f, p1 = 0.f, p2 = 0.f, p3 = 0.f;
#pragma unroll
        for (int c = 0; c < 16; ++c) {
            F4H hu; hu.f4 = hr[c];
            p0 = dot2(wn[4 * c + 0], hu.h[0], p0);
            p1 = dot2(wn[4 * c + 1], hu.h[1], p1);
            p2 = dot2(wn[4 * c + 2], hu.h[2], p2);
            p3 = dot2(wn[4 * c + 3], hu.h[3], p3);
        }
        out[r * OO + n] = ((p0 + p1) + (p2 + p3)) + bl;
    }
}

extern "C" void kernel_launch(void* const* d_in, const int* in_sizes, int n_in,
                              void* d_out, int out_size, void* d_ws, size_t ws_size,
                              hipStream_t stream) {
    (void)in_sizes; (void)n_in; (void)out_size;
    const float* x      = (const float*)d_in[0];
    const float* Wx_out = (const float*)d_in[1];
    const float* Wh_out = (const float*)d_in[2];
    const float* b_out  = (const float*)d_in[3];
    const float* Wx_in  = (const float*)d_in[4];
    const float* Wh_in  = (const float*)d_in[5];
    const float* b_in   = (const float*)d_in[6];
    const float* W_lin  = (const float*)d_in[7];
    const float* b_lin  = (const float*)d_in[8];
    float* out = (float*)d_out;

    const size_t hws_b = (size_t)BB * SS * (HH / 2) * sizeof(f16x2);  // 64 MB
    const size_t hst_b = (size_t)BB * (HH / 2) * sizeof(f16x2);       // 32 KB
    const size_t cst_b = (size_t)BB * HH * sizeof(float);             // 64 KB
    const int tcs[5] = {2048, 1024, 512, 256, 128};

    int Tc = 0;
    bool proj_out = false;
    if (d_ws != nullptr) {
        for (int i = 0; i < 5 && Tc == 0; ++i) {
            const size_t gxb = (size_t)BB * tcs[i] * GG * sizeof(float);
            if (ws_size >= hws_b + hst_b + 2 * cst_b + gxb) { Tc = tcs[i]; proj_out = true; }
        }
        for (int i = 0; i < 5 && Tc == 0; ++i) {
            const size_t gxb = (size_t)BB * tcs[i] * GG * sizeof(float);
            if (ws_size >= hst_b + 2 * cst_b + gxb) Tc = tcs[i];
        }
    }

    if (Tc != 0) {
        char* p = (char*)d_ws;
        f16x2* hws = nullptr;
        if (proj_out) { hws = (f16x2*)p; p += hws_b; }
        f16x2* hst = (f16x2*)p; p += hst_b;
        float* cst  = (float*)p; p += cst_b;
        float* cnst = (float*)p; p += cst_b;
        float* gx   = (float*)p;
        const int nchunk = Tc / 128;

        for (int t0 = 0; t0 < SS; t0 += Tc) {
            nlstm_gatex<<<dim3(BB * nchunk), dim3(512), 0, stream>>>(
                x, Wx_out, b_out, gx, t0, nchunk);
            if (proj_out)
                nlstm_scan_seg<false><<<dim3(BB), dim3(512), 0, stream>>>(
                    Wh_out, Wx_in, Wh_in, b_in, W_lin, b_lin, gx, out,
                    hws, hst, cst, cnst, t0, t0 + Tc, Tc);
            else
                nlstm_scan_seg<true><<<dim3(BB), dim3(512), 0, stream>>>(
                    Wh_out, Wx_in, Wh_in, b_in, W_lin, b_lin, gx, out,
                    nullptr, hst, cst, cnst, t0, t0 + Tc, Tc);
        }
        if (proj_out)
            nlstm_proj<<<dim3(512), dim3(256), 0, stream>>>(hws, W_lin, b_lin, out);
    } else {
        nlstm_fused<<<dim3(BB), dim3(512), 0, stream>>>(
            x, Wx_out, Wh_out, b_out, Wx_in, Wh_in, b_in, W_lin, b_lin, out);
    }
}

// Round 10
// 3577.341 us; speedup vs baseline: 4.0886x; 1.0738x over previous
//
#include <hip/hip_runtime.h>
#include <hip/hip_fp16.h>

#define BB 128
#define II 64
#define SS 2048
#define HH 128
#define GG 512   // 4*H
#define OO 64

typedef _Float16 f16x2 __attribute__((ext_vector_type(2)));
union F4H { float4 f4; f16x2 h[4]; };

__device__ __forceinline__ f16x2 pack2(float a, float b) {
    f16x2 r; r.x = (_Float16)a; r.y = (_Float16)b; return r;
}

__device__ __forceinline__ float dot2(f16x2 w, f16x2 v, float c) {
#if __has_builtin(__builtin_amdgcn_fdot2)
    return __builtin_amdgcn_fdot2(w, v, c, false);
#else
    return fmaf((float)w.x, (float)v.x, fmaf((float)w.y, (float)v.y, c));
#endif
}

__device__ __forceinline__ float tanh_f(float v) {
    float a = fabsf(v);
    float e = __expf(-2.0f * a);
    float r = (1.0f - e) * __builtin_amdgcn_rcpf(1.0f + e);
    return v < 0.0f ? -r : r;
}

// generic quad DPP: lane i reads lane (quad_base + perm[i&3]), pattern P packed
template<int P>
__device__ __forceinline__ float qp(float v) {
    return __int_as_float(__builtin_amdgcn_mov_dpp(
        __float_as_int(v), P, 0xF, 0xF, true));
}
// quad broadcast of lane C
template<int C>
__device__ __forceinline__ float qb(float v) { return qp<0x55 * C>(v); }
// DPP row rotate-LEFT by N within 16-lane rows: lane i <- lane (i+N)&15.
// (row_ror:N is lane i <- lane (i-N)&15 — that direction broke R2.)
template<int N>
__device__ __forceinline__ float rolN(float v) {
    return __int_as_float(__builtin_amdgcn_mov_dpp(
        __float_as_int(v), 0x120 + (16 - N), 0xF, 0xF, true));
}

// LDS-only barrier: avoids __syncthreads()'s vmcnt(0) drain of in-flight
// global loads/stores. LDS ordering (hb/xib/hib) is all we need.
__device__ __forceinline__ void barrier_lds() {
    asm volatile("s_waitcnt lgkmcnt(0)\n\ts_barrier" ::: "memory");
}

// ---------------------------------------------------------------------------
// Time-parallel precompute: gx[bb][tl][j] = b_out[jcol] + x[bb,:,T]·Wx_out[:,jcol]
// stored chunk-local, PERMUTED by scan thread index j. (unchanged from R9)
__global__ void __launch_bounds__(512)
nlstm_gatex(const float* __restrict__ x, const float* __restrict__ Wx_out,
            const float* __restrict__ b_out, float* __restrict__ gx,
            int t0, int nchunk)
{
    const int bb  = blockIdx.x / nchunk;
    const int tcw = blockIdx.x % nchunk;
    const int j   = threadIdx.x;
    const int u = j >> 2, g = j & 3;
    const int jcol = g * HH + u;

    __shared__ __align__(16) f16x2 xs[128][36];   // 18.4 KB

    f16x2 wxo[II / 2];
#pragma unroll
    for (int m = 0; m < II / 2; ++m)
        wxo[m] = pack2(Wx_out[(2 * m) * GG + jcol],
                       Wx_out[(2 * m + 1) * GG + jcol]);
    const float bo = b_out[jcol];

    const float* xrow = x + (size_t)bb * II * SS;
    const int T0 = t0 + tcw * 128;
#pragma unroll
    for (int r = 0; r < 8; ++r) {
        const int idx = r * 512 + j;
        const int m = idx >> 7, tt = idx & 127;
        xs[tt][m] = pack2(xrow[(size_t)(2 * m) * SS + T0 + tt],
                          xrow[(size_t)(2 * m + 1) * SS + T0 + tt]);
    }
    __syncthreads();

#pragma unroll 1
    for (int tt = 0; tt < 128; ++tt) {
        const float4* xc4 = (const float4*)&xs[tt][0];
        float a0 = bo, a1 = 0.f, a2 = 0.f, a3 = 0.f;
#pragma unroll
        for (int c = 0; c < 8; ++c) {
            F4H xu; xu.f4 = xc4[c];
            a0 = dot2(wxo[4 * c + 0], xu.h[0], a0);
            a1 = dot2(wxo[4 * c + 1], xu.h[1], a1);
            a2 = dot2(wxo[4 * c + 2], xu.h[2], a2);
            a3 = dot2(wxo[4 * c + 3], xu.h[3], a3);
        }
        const float v = (a0 + a1) + (a2 + a3);
        const size_t tl = (size_t)tcw * 128 + tt;
        gx[((size_t)bb * nchunk * 128 + tl) * GG + j] = v;
    }
}

// ---------------------------------------------------------------------------
// Segmented scan, R10: QUAD SPLIT-K. R9 was LDS-instruction-throughput bound
// (48 broadcast b128 reads/thread/step x 8 waves ~ 384 LDS instr/CU/step at
// ~10-12cy each == the whole step time). Now lane g of quad u holds ALL 4 of
// the quad's gate columns x the k-slice {chunks g,g+4,g+8,g+12} (same 192
// VGPRs, different content), reads ONLY its k-slice (4 b128 outer + 8 inner
// vs 16+32), computes 4 partial dots, and a quad butterfly all-reduce
// (quad_perm 0xB1=[1,0,3,2], 0x4E=[2,3,0,1]; pure VALU) recovers each lane's
// own-column total. Chunk interleave g+4*c4 -> per-instruction addresses span
// banks 0..15 disjointly (conflict-free). Downstream logic unchanged.
//
// REGISTER CLIFF (R4/R5/R6): any net-positive live-register change spills
// loop-resident values to L2-scratch (~2x cost). This change is reg-neutral.
template<bool PROJ_IN>
__global__ void __launch_bounds__(512)
__attribute__((amdgpu_waves_per_eu(2)))
nlstm_scan_seg(
    const float* __restrict__ Wh_out,
    const float* __restrict__ Wx_in, const float* __restrict__ Wh_in,
    const float* __restrict__ b_in,
    const float* __restrict__ W_lin, const float* __restrict__ b_lin,
    const float* __restrict__ gx, float* __restrict__ out,
    f16x2* __restrict__ hws, f16x2* __restrict__ hst,
    float* __restrict__ cst, float* __restrict__ cnst,
    int t0, int t1, int Tc)
{
    const int b = blockIdx.x;
    const int j = threadIdx.x;
    const int u = j >> 2;          // hidden unit (quad index)
    const int g = j & 3;           // gate AND k-slice index: 0=i 1=f 2=o 3=g
    const int jcol = g * HH + u;   // this lane's own gate column

    __shared__ __align__(16) f16x2 hb[HH / 2];         // h fp16
    __shared__ __align__(16) f16x2 xib[HH / 2];        // x_in fp16
    __shared__ __align__(16) f16x2 hib[HH / 2];        // h_in fp16

    // ---- split-K register weights: [col c of quad][k-slice of lane g] ----
    // who[c][4*c4+e] covers k = 8*(g+4*c4) + {2e, 2e+1} of column c*HH+u.
    f16x2 who[4][16];   // Wh_out  (64 regs)
    f16x2 wxi[4][16];   // Wx_in   (64 regs)
    f16x2 whi[4][16];   // Wh_in   (64 regs)
#pragma unroll
    for (int c = 0; c < 4; ++c)
#pragma unroll
        for (int c4 = 0; c4 < 4; ++c4)
#pragma unroll
            for (int e = 0; e < 4; ++e) {
                const int k0 = 8 * (g + 4 * c4) + 2 * e;
                const int cc = c * HH + u;
                who[c][4 * c4 + e] = pack2(Wh_out[(size_t)k0 * GG + cc],
                                           Wh_out[(size_t)(k0 + 1) * GG + cc]);
                wxi[c][4 * c4 + e] = pack2(Wx_in[(size_t)k0 * GG + cc],
                                           Wx_in[(size_t)(k0 + 1) * GG + cc]);
                whi[c][4 * c4 + e] = pack2(Wh_in[(size_t)k0 * GG + cc],
                                           Wh_in[(size_t)(k0 + 1) * GG + cc]);
            }

    const float bi2 = b_in[jcol];

    // in-scan projection state (PROJ_IN mode)
    const int   pn = j >> 3;
    const int   ps = j & 7;
    float bl = 0.f;
    F4H wl[2];
    if constexpr (PROJ_IN) {
        bl = b_lin[pn];
#pragma unroll
        for (int q = 0; q < 2; ++q) {
            const int c = 2 * ps + q;
#pragma unroll
            for (int r = 0; r < 4; ++r)
                wl[q].h[r] = pack2(W_lin[pn * HH + 8 * c + 2 * r],
                                   W_lin[pn * HH + 8 * c + 2 * r + 1]);
        }
    }

    float* orow = out + (size_t)b * SS * OO;
    f16x2* hrow = (PROJ_IN ? (f16x2*)nullptr : hws + (size_t)b * SS * (HH / 2));
    const float* gxrow = gx + (size_t)b * Tc * GG;

    // ---- state load ----
    float c_reg, cn_reg;
    if (t0 == 0) {
        if (j < HH / 2) hb[j] = pack2(0.f, 0.f);
        c_reg = 0.f; cn_reg = 0.f;
    } else {
        if (j < HH / 2) hb[j] = hst[b * (HH / 2) + j];
        c_reg  = cst[b * HH + u];
        cn_reg = cnst[b * HH + u];
    }
    __syncthreads();

    const float4* hb4 = (const float4*)hb;
    const float4* xi4 = (const float4*)xib;
    const float4* hi4 = (const float4*)hib;
    const bool isT = (g == 3);

    float gx_cur = gxrow[j];

#pragma unroll 1
    for (int t = t0; t < t1; ++t) {
        const int tl = t - t0;

        // ---- prefetch next gx element (coalesced 4B/lane) ----
        const int tln = (tl + 1 < Tc) ? tl + 1 : tl;
        const float gx_nxt = gxrow[(size_t)tln * GG + j];

        // ---- outer gates, split-K: 4 partial dots over this lane's slice ----
        float p0 = 0.f, p1 = 0.f, p2 = 0.f, p3 = 0.f;
#pragma unroll
        for (int c4 = 0; c4 < 4; ++c4) {
            F4H hu; hu.f4 = hb4[g + 4 * c4];   // 4 b128 (was 16)
#pragma unroll
            for (int e = 0; e < 4; ++e) {
                p0 = dot2(who[0][4 * c4 + e], hu.h[e], p0);
                p1 = dot2(who[1][4 * c4 + e], hu.h[e], p1);
                p2 = dot2(who[2][4 * c4 + e], hu.h[e], p2);
                p3 = dot2(who[3][4 * c4 + e], hu.h[e], p3);
            }
        }
        // quad butterfly all-reduce; then each lane keeps its own column g
        p0 += qp<0xB1>(p0); p1 += qp<0xB1>(p1);
        p2 += qp<0xB1>(p2); p3 += qp<0xB1>(p3);
        p0 += qp<0x4E>(p0); p1 += qp<0x4E>(p1);
        p2 += qp<0x4E>(p2); p3 += qp<0x4E>(p3);
        const float totO = (g & 1) ? ((g & 2) ? p3 : p1)
                                   : ((g & 2) ? p2 : p0);
        float acc = totO + gx_cur;

        // unified activation: g<3 sigmoid, g==3 tanh = 2*sigm(2x)-1
        float ap = isT ? 2.f * acc : acc;
        float s  = __builtin_amdgcn_rcpf(1.f + __expf(-ap));
        float av = isT ? fmaf(2.f, s, -1.f) : s;

        // gate combination inside the quad (no LDS, no barrier)
        float vi = qb<0>(av), vf = qb<1>(av), vo = qb<2>(av), vg = qb<3>(av);
        float x_in    = vi * vg;        // i * g
        float h_in    = vf * c_reg;     // f * c
        float o_outer = vo;             // kept for h_new

        // ---- in-scan projection of h_{t-1} (PROJ_IN mode) ----
        if constexpr (PROJ_IN) {
            float q0 = 0.f, q1 = 0.f;
            F4H hu0; hu0.f4 = hb4[2 * ps];
            F4H hu1; hu1.f4 = hb4[2 * ps + 1];
            q0 = dot2(wl[0].h[0], hu0.h[0], q0);
            q1 = dot2(wl[0].h[1], hu0.h[1], q1);
            q0 = dot2(wl[0].h[2], hu0.h[2], q0);
            q1 = dot2(wl[0].h[3], hu0.h[3], q1);
            q0 = dot2(wl[1].h[0], hu1.h[0], q0);
            q1 = dot2(wl[1].h[1], hu1.h[1], q1);
            q0 = dot2(wl[1].h[2], hu1.h[2], q0);
            q1 = dot2(wl[1].h[3], hu1.h[3], q1);
            float p = q0 + q1;
            p += rolN<4>(p);
            p += rolN<2>(p);
            p += rolN<1>(p);
            if (ps == 0 && t > 0) orow[(size_t)(t - 1) * OO + pn] = p + bl;
        }

        // write x_in/h_in pairs (lane j=8k packs units 2k,2k+1 via DPP rol4)
        float xin_n = rolN<4>(x_in);
        float hin_n = rolN<4>(h_in);
        if ((j & 7) == 0) {
            xib[u >> 1] = pack2(x_in, xin_n);
            hib[u >> 1] = pack2(h_in, hin_n);
        }
        barrier_lds();   // B_a: xib/hib visible; hb readers done before write

        // ---- inner gates, split-K: slice of x_in part + h_in part ----
        float s0 = 0.f, s1 = 0.f, s2 = 0.f, s3 = 0.f;
#pragma unroll
        for (int c4 = 0; c4 < 4; ++c4) {
            F4H xu; xu.f4 = xi4[g + 4 * c4];   // 4 b128 (was 16)
#pragma unroll
            for (int e = 0; e < 4; ++e) {
                s0 = dot2(wxi[0][4 * c4 + e], xu.h[e], s0);
                s1 = dot2(wxi[1][4 * c4 + e], xu.h[e], s1);
                s2 = dot2(wxi[2][4 * c4 + e], xu.h[e], s2);
                s3 = dot2(wxi[3][4 * c4 + e], xu.h[e], s3);
            }
        }
#pragma unroll
        for (int c4 = 0; c4 < 4; ++c4) {
            F4H hu2; hu2.f4 = hi4[g + 4 * c4]; // 4 b128 (was 16)
#pragma unroll
            for (int e = 0; e < 4; ++e) {
                s0 = dot2(whi[0][4 * c4 + e], hu2.h[e], s0);
                s1 = dot2(whi[1][4 * c4 + e], hu2.h[e], s1);
                s2 = dot2(whi[2][4 * c4 + e], hu2.h[e], s2);
                s3 = dot2(whi[3][4 * c4 + e], hu2.h[e], s3);
            }
        }
        s0 += qp<0xB1>(s0); s1 += qp<0xB1>(s1);
        s2 += qp<0xB1>(s2); s3 += qp<0xB1>(s3);
        s0 += qp<0x4E>(s0); s1 += qp<0x4E>(s1);
        s2 += qp<0x4E>(s2); s3 += qp<0x4E>(s3);
        const float totI = (g & 1) ? ((g & 2) ? s3 : s1)
                                   : ((g & 2) ? s2 : s0);
        float acc2 = totI + bi2;

        float ap2 = isT ? 2.f * acc2 : acc2;
        float s2a = __builtin_amdgcn_rcpf(1.f + __expf(-ap2));
        float av2 = isT ? fmaf(2.f, s2a, -1.f) : s2a;

        // state update inside the quad (no LDS, no barrier)
        float ii = qb<0>(av2), fi = qb<1>(av2), oi = qb<2>(av2), gg = qb<3>(av2);
        float cn_new = fmaf(fi, cn_reg, ii * gg);
        cn_reg = cn_new;
        float c_new = oi * tanh_f(cn_new);
        c_reg = c_new;
        float h_new = o_outer * tanh_f(c_new);

        float hn_n = rolN<4>(h_new);
        if ((j & 7) == 0) {
            f16x2 hp = pack2(h_new, hn_n);
            hb[u >> 1] = hp;
            if constexpr (!PROJ_IN)
                hrow[(size_t)t * (HH / 2) + (j >> 3)] = hp;  // h_t -> ws
        }
        gx_cur = gx_nxt;
        barrier_lds();   // B_b: h_t visible
    }

    // ---- state save (hb stable after final B_b) ----
    if (j < HH / 2) hst[b * (HH / 2) + j] = hb[j];
    if (g == 0) { cst[b * HH + u] = c_reg; cnst[b * HH + u] = cn_reg; }

    // ---- final projection: out[S-1] (PROJ_IN mode, last segment only) ----
    if constexpr (PROJ_IN) {
        if (t1 == SS) {
            float q0 = 0.f, q1 = 0.f;
            F4H hu0; hu0.f4 = hb4[2 * ps];
            F4H hu1; hu1.f4 = hb4[2 * ps + 1];
            q0 = dot2(wl[0].h[0], hu0.h[0], q0);
            q1 = dot2(wl[0].h[1], hu0.h[1], q1);
            q0 = dot2(wl[0].h[2], hu0.h[2], q0);
            q1 = dot2(wl[0].h[3], hu0.h[3], q1);
            q0 = dot2(wl[1].h[0], hu1.h[0], q0);
            q1 = dot2(wl[1].h[1], hu1.h[1], q1);
            q0 = dot2(wl[1].h[2], hu1.h[2], q0);
            q1 = dot2(wl[1].h[3], hu1.h[3], q1);
            float p = q0 + q1;
            p += rolN<4>(p);
            p += rolN<2>(p);
            p += rolN<1>(p);
            if (ps == 0) orow[(size_t)(SS - 1) * OO + pn] = p + bl;
        }
    }
}

// ---------------------------------------------------------------------------
// Fully fused fallback (R3/R7-verified path) — UNTOUCHED (never dispatched
// given ws >= ~98 MB evidence from R9; kept for safety).
__global__ void __launch_bounds__(512)
__attribute__((amdgpu_waves_per_eu(2)))
nlstm_fused(
    const float* __restrict__ x,
    const float* __restrict__ Wx_out, const float* __restrict__ Wh_out,
    const float* __restrict__ b_out,
    const float* __restrict__ Wx_in, const float* __restrict__ Wh_in,
    const float* __restrict__ b_in,
    const float* __restrict__ W_lin, const float* __restrict__ b_lin,
    float* __restrict__ out)
{
    const int b = blockIdx.x;
    const int j = threadIdx.x;
    const int u = j >> 2, g = j & 3;
    const int jcol = g * HH + u;

    __shared__ __align__(16) float4 wxf[8 * 512];
    __shared__ __align__(16) f16x2 xt[2][16][36];
    __shared__ __align__(16) f16x2 hb[HH / 2];
    __shared__ __align__(16) f16x2 xib[HH / 2];
    __shared__ __align__(16) f16x2 hib[HH / 2];

    f16x2 who[HH / 2], wxi[HH / 2], whi[HH / 2];
#pragma unroll
    for (int m = 0; m < HH / 2; ++m)
        who[m] = pack2(Wh_out[(2 * m) * GG + jcol], Wh_out[(2 * m + 1) * GG + jcol]);
#pragma unroll
    for (int m = 0; m < HH / 2; ++m)
        wxi[m] = pack2(Wx_in[(2 * m) * GG + jcol], Wx_in[(2 * m + 1) * GG + jcol]);
#pragma unroll
    for (int m = 0; m < HH / 2; ++m)
        whi[m] = pack2(Wh_in[(2 * m) * GG + jcol], Wh_in[(2 * m + 1) * GG + jcol]);

    const float bo = b_out[jcol];
    const float bi2 = b_in[jcol];
    const int pn = j >> 3, ps = j & 7;
    const float bl = b_lin[pn];
    F4H wl[2];
#pragma unroll
    for (int q = 0; q < 2; ++q) {
        const int c = 2 * ps + q;
#pragma unroll
        for (int r = 0; r < 4; ++r)
            wl[q].h[r] = pack2(W_lin[pn * HH + 8 * c + 2 * r],
                               W_lin[pn * HH + 8 * c + 2 * r + 1]);
    }
#pragma unroll
    for (int c = 0; c < 8; ++c) {
        F4H w4;
#pragma unroll
        for (int q = 0; q < 4; ++q)
            w4.h[q] = pack2(Wx_out[(8 * c + 2 * q) * GG + jcol],
                            Wx_out[(8 * c + 2 * q + 1) * GG + jcol]);
        wxf[c * 512 + j] = w4.f4;
    }

    const float* xrow = x + (size_t)b * II * SS;
    float* orow = out + (size_t)b * SS * OO;
    const int xm = j >> 4, xtl = j & 15;
    const float* xg0 = xrow + (size_t)(2 * xm) * SS + xtl;
    const float* xg1 = xrow + (size_t)(2 * xm + 1) * SS + xtl;

    xt[0][xtl][xm] = pack2(xg0[0], xg1[0]);
    if (j < HH / 2) hb[j] = pack2(0.f, 0.f);
    __syncthreads();

    float c_reg = 0.f, cn_reg = 0.f;
    const float4* hb4 = (const float4*)hb;
    const float4* xi4 = (const float4*)xib;
    const float4* hi4 = (const float4*)hib;
    const bool isT = (g == 3);
    float pr0 = 0.f, pr1 = 0.f;

#pragma unroll 1
    for (int t = 0; t < SS; ++t) {
        const int stl = t & 15;
        const int tb = (t >> 4) & 1;
        if (stl == 0) {
            const int Tn = (t + 16 < SS) ? t + 16 : t;
            pr0 = xg0[Tn];
            pr1 = xg1[Tn];
        }
        const float4* xc4 = (const float4*)&xt[tb][stl][0];
        float a0 = bo, a1 = 0.f, a2 = 0.f, a3 = 0.f;
#pragma unroll
        for (int c = 0; c < 8; ++c) {
            F4H xu; xu.f4 = xc4[c];
            F4H wu; wu.f4 = wxf[c * 512 + j];
            a0 = dot2(wu.h[0], xu.h[0], a0);
            a1 = dot2(wu.h[1], xu.h[1], a1);
            a2 = dot2(wu.h[2], xu.h[2], a2);
            a3 = dot2(wu.h[3], xu.h[3], a3);
        }
#pragma unroll
        for (int c = 0; c < 16; ++c) {
            F4H hu; hu.f4 = hb4[c];
            a0 = dot2(who[4 * c + 0], hu.h[0], a0);
            a1 = dot2(who[4 * c + 1], hu.h[1], a1);
            a2 = dot2(who[4 * c + 2], hu.h[2], a2);
            a3 = dot2(who[4 * c + 3], hu.h[3], a3);
        }
        float acc = (a0 + a1) + (a2 + a3);
        float ap = isT ? 2.f * acc : acc;
        float s = __builtin_amdgcn_rcpf(1.f + __expf(-ap));
        float av = isT ? fmaf(2.f, s, -1.f) : s;
        float vi = qb<0>(av), vf = qb<1>(av), vo = qb<2>(av), vg = qb<3>(av);
        float x_in = vi * vg, h_in = vf * c_reg, o_outer = vo;

        float p0 = 0.f, p1 = 0.f;
        {
            F4H hu0; hu0.f4 = hb4[2 * ps];
            F4H hu1; hu1.f4 = hb4[2 * ps + 1];
            p0 = dot2(wl[0].h[0], hu0.h[0], p0);
            p1 = dot2(wl[0].h[1], hu0.h[1], p1);
            p0 = dot2(wl[0].h[2], hu0.h[2], p0);
            p1 = dot2(wl[0].h[3], hu0.h[3], p1);
            p0 = dot2(wl[1].h[0], hu1.h[0], p0);
            p1 = dot2(wl[1].h[1], hu1.h[1], p1);
            p0 = dot2(wl[1].h[2], hu1.h[2], p0);
            p1 = dot2(wl[1].h[3], hu1.h[3], p1);
        }
        float p = p0 + p1;
        p += rolN<4>(p);
        p += rolN<2>(p);
        p += rolN<1>(p);
        if (ps == 0 && t > 0) orow[(size_t)(t - 1) * OO + pn] = p + bl;

        float xin_n = rolN<4>(x_in);
        float hin_n = rolN<4>(h_in);
        if ((j & 7) == 0) {
            xib[u >> 1] = pack2(x_in, xin_n);
            hib[u >> 1] = pack2(h_in, hin_n);
        }
        barrier_lds();

        float b0 = 0.f, b1 = 0.f, b2 = 0.f, b3 = 0.f;
#pragma unroll
        for (int c = 0; c < 16; ++c) {
            F4H xu; xu.f4 = xi4[c];
            b0 = dot2(wxi[4 * c + 0], xu.h[0], b0);
            b1 = dot2(wxi[4 * c + 1], xu.h[1], b1);
            b2 = dot2(wxi[4 * c + 2], xu.h[2], b2);
            b3 = dot2(wxi[4 * c + 3], xu.h[3], b3);
        }
#pragma unroll
        for (int c = 0; c < 16; ++c) {
            F4H hu; hu.f4 = hi4[c];
            b0 = dot2(whi[4 * c + 0], hu.h[0], b0);
            b1 = dot2(whi[4 * c + 1], hu.h[1], b1);
            b2 = dot2(whi[4 * c + 2], hu.h[2], b2);
            b3 = dot2(whi[4 * c + 3], hu.h[3], b3);
        }
        float acc2 = ((b0 + b1) + (b2 + b3)) + bi2;
        float ap2 = isT ? 2.f * acc2 : acc2;
        float s2 = __builtin_amdgcn_rcpf(1.f + __expf(-ap2));
        float av2 = isT ? fmaf(2.f, s2, -1.f) : s2;
        float ii = qb<0>(av2), fi = qb<1>(av2), oi = qb<2>(av2), gg = qb<3>(av2);
        float cn_new = fmaf(fi, cn_reg, ii * gg);
        cn_reg = cn_new;
        float c_new = oi * tanh_f(cn_new);
        c_reg = c_new;
        float h_new = o_outer * tanh_f(c_new);
        float hn_n = rolN<4>(h_new);
        if ((j & 7) == 0) hb[u >> 1] = pack2(h_new, hn_n);
        if (stl == 0) xt[tb ^ 1][xtl][xm] = pack2(pr0, pr1);
        barrier_lds();
    }
    {
        float p0 = 0.f, p1 = 0.f;
        F4H hu0; hu0.f4 = hb4[2 * ps];
        F4H hu1; hu1.f4 = hb4[2 * ps + 1];
        p0 = dot2(wl[0].h[0], hu0.h[0], p0);
        p1 = dot2(wl[0].h[1], hu0.h[1], p1);
        p0 = dot2(wl[0].h[2], hu0.h[2], p0);
        p1 = dot2(wl[0].h[3], hu0.h[3], p1);
        p0 = dot2(wl[1].h[0], hu1.h[0], p0);
        p1 = dot2(wl[1].h[1], hu1.h[1], p1);
        p0 = dot2(wl[1].h[2], hu1.h[2], p0);
        p1 = dot2(wl[1].h[3], hu1.h[3], p1);
        float p = p0 + p1;
        p += rolN<4>(p);
        p += rolN<2>(p);
        p += rolN<1>(p);
        if (ps == 0) orow[(size_t)(SS - 1) * OO + pn] = p + bl;
    }
}

// Post-scan projection: out[r, n] = h[r,:] @ W_lin[n,:] + b_lin[n]. (unchanged)
__global__ void __launch_bounds__(256)
nlstm_proj(const f16x2* __restrict__ hws, const float* __restrict__ W_lin,
           const float* __restrict__ b_lin, float* __restrict__ out)
{
    const int n  = threadIdx.x & 63;
    const int rg = threadIdx.x >> 6;

    f16x2 wn[HH / 2];
#pragma unroll
    for (int k = 0; k < HH / 2; ++k)
        wn[k] = pack2(W_lin[n * HH + 2 * k], W_lin[n * HH + 2 * k + 1]);
    const float bl = b_lin[n];

    const size_t r0 = (size_t)blockIdx.x * 512 + (size_t)rg * 128;
#pragma unroll 1
    for (int rr = 0; rr < 128; ++rr) {
        const size_t r = r0 + rr;
        const float4* hr = (const float4*)(hws + r * (HH / 2));
        float p0 = 0.f, p1 = 0.f, p2 = 0.f, p3 = 0.f;
#pragma unroll
        for (int c = 0; c < 16; ++c) {
            F4H hu; hu.f4 = hr[c];
            p0 = dot2(wn[4 * c + 0], hu.h[0], p0);
            p1 = dot2(wn[4 * c + 1], hu.h[1], p1);
            p2 = dot2(wn[4 * c + 2], hu.h[2], p2);
            p3 = dot2(wn[4 * c + 3], hu.h[3], p3);
        }
        out[r * OO + n] = ((p0 + p1) + (p2 + p3)) + bl;
    }
}

extern "C" void kernel_launch(void* const* d_in, const int* in_sizes, int n_in,
                              void* d_out, int out_size, void* d_ws, size_t ws_size,
                              hipStream_t stream) {
    (void)in_sizes; (void)n_in; (void)out_size;
    const float* x      = (const float*)d_in[0];
    const float* Wx_out = (const float*)d_in[1];
    const float* Wh_out = (const float*)d_in[2];
    const float* b_out  = (const float*)d_in[3];
    const float* Wx_in  = (const float*)d_in[4];
    const float* Wh_in  = (const float*)d_in[5];
    const float* b_in   = (const float*)d_in[6];
    const float* W_lin  = (const float*)d_in[7];
    const float* b_lin  = (const float*)d_in[8];
    float* out = (float*)d_out;

    const size_t hws_b = (size_t)BB * SS * (HH / 2) * sizeof(f16x2);  // 64 MB
    const size_t hst_b = (size_t)BB * (HH / 2) * sizeof(f16x2);       // 32 KB
    const size_t cst_b = (size_t)BB * HH * sizeof(float);             // 64 KB
    const int tcs[5] = {2048, 1024, 512, 256, 128};

    int Tc = 0;
    bool proj_out = false;
    if (d_ws != nullptr) {
        for (int i = 0; i < 5 && Tc == 0; ++i) {
            const size_t gxb = (size_t)BB * tcs[i] * GG * sizeof(float);
            if (ws_size >= hws_b + hst_b + 2 * cst_b + gxb) { Tc = tcs[i]; proj_out = true; }
        }
        for (int i = 0; i < 5 && Tc == 0; ++i) {
            const size_t gxb = (size_t)BB * tcs[i] * GG * sizeof(float);
            if (ws_size >= hst_b + 2 * cst_b + gxb) Tc = tcs[i];
        }
    }

    if (Tc != 0) {
        char* p = (char*)d_ws;
        f16x2* hws = nullptr;
        if (proj_out) { hws = (f16x2*)p; p += hws_b; }
        f16x2* hst = (f16x2*)p; p += hst_b;
        float* cst  = (float*)p; p += cst_b;
        float* cnst = (float*)p; p += cst_b;
        float* gx   = (float*)p;
        const int nchunk = Tc / 128;

        for (int t0 = 0; t0 < SS; t0 += Tc) {
            nlstm_gatex<<<dim3(BB * nchunk), dim3(512), 0, stream>>>(
                x, Wx_out, b_out, gx, t0, nchunk);
            if (proj_out)
                nlstm_scan_seg<false><<<dim3(BB), dim3(512), 0, stream>>>(
                    Wh_out, Wx_in, Wh_in, b_in, W_lin, b_lin, gx, out,
                    hws, hst, cst, cnst, t0, t0 + Tc, Tc);
            else
                nlstm_scan_seg<true><<<dim3(BB), dim3(512), 0, stream>>>(
                    Wh_out, Wx_in, Wh_in, b_in, W_lin, b_lin, gx, out,
                    nullptr, hst, cst, cnst, t0, t0 + Tc, Tc);
        }
        if (proj_out)
            nlstm_proj<<<dim3(512), dim3(256), 0, stream>>>(hws, W_lin, b_lin, out);
    } else {
        nlstm_fused<<<dim3(BB), dim3(512), 0, stream>>>(
            x, Wx_out, Wh_out, b_out, Wx_in, Wh_in, b_in, W_lin, b_lin, out);
    }
}